// Round 1
// baseline (863.059 us; speedup 1.0000x reference)
//
#include <hip/hip_runtime.h>

// SpatialAwareAttention — fp32 correctness-first baseline.
// B=4, L=1024, D=768, H=12, hd=64, BIAS_HIDDEN=32.
//
// Pipeline:
//   1) gemm768 x3 : Q/K/V = x@W + b, written as [B*H][L][64] into d_ws
//   2) attn_fused : flash-style attention per (b,h,i-tile), spatial-bias MLP
//                   recomputed in-register (avoids 201MB bias tensor)
//   3) gemm768    : out = AO @ Wo + bo  -> d_out
//
// All fp32 on the vector ALU (no fp32-input MFMA on CDNA4).

#define BH 48          // B*H
#define LSEQ 1024
#define MROWS 4096     // B*L
#define DMOD 768

// ---------------------------------------------------------------------------
// C[4096x768] = A[4096x768] @ W[768x768] + bvec
// qkv_layout==1: write C[m][n] to out[((b*12+h)*1024+l)*64+d]
// ---------------------------------------------------------------------------
__global__ __launch_bounds__(256) void gemm768(const float* __restrict__ A,
                                               const float* __restrict__ W,
                                               const float* __restrict__ bvec,
                                               float* __restrict__ C,
                                               int qkv_layout) {
    __shared__ float As[16][68];   // transposed A tile: As[k][m], pad 68 keeps 16B align
    __shared__ float Bs[16][68];   // Bs[k][n]

    const int t  = threadIdx.x;
    const int tx = t & 15, ty = t >> 4;
    const int n0 = blockIdx.x * 64, m0 = blockIdx.y * 64;

    float acc[4][4];
#pragma unroll
    for (int i = 0; i < 4; ++i)
#pragma unroll
        for (int j = 0; j < 4; ++j) acc[i][j] = 0.f;

    const int ar  = t >> 2;          // 0..63 : A tile row
    const int akq = (t & 3) << 2;    // 0,4,8,12 : A tile k quad
    const int bkr = t >> 4;          // 0..15 : B tile k row
    const int bnq = (t & 15) << 2;   // 0..60 : B tile n quad

    for (int k0 = 0; k0 < 768; k0 += 16) {
        __syncthreads();
        float4 av = *(const float4*)&A[(m0 + ar) * 768 + k0 + akq];
        As[akq + 0][ar] = av.x;
        As[akq + 1][ar] = av.y;
        As[akq + 2][ar] = av.z;
        As[akq + 3][ar] = av.w;
        *(float4*)&Bs[bkr][bnq] = *(const float4*)&W[(k0 + bkr) * 768 + n0 + bnq];
        __syncthreads();
#pragma unroll
        for (int kk = 0; kk < 16; ++kk) {
            float4 a4 = *(const float4*)&As[kk][ty << 2];
            float4 b4 = *(const float4*)&Bs[kk][tx << 2];
            float aa[4] = {a4.x, a4.y, a4.z, a4.w};
            float bb[4] = {b4.x, b4.y, b4.z, b4.w};
#pragma unroll
            for (int i = 0; i < 4; ++i)
#pragma unroll
                for (int j = 0; j < 4; ++j)
                    acc[i][j] = fmaf(aa[i], bb[j], acc[i][j]);
        }
    }

    const int h = n0 >> 6;  // n-tile is 64-wide & 64-aligned -> one head per block col
#pragma unroll
    for (int i = 0; i < 4; ++i) {
        const int m = m0 + (ty << 2) + i;
        const int n = n0 + (tx << 2);
        float4 val;
        val.x = acc[i][0] + bvec[n + 0];
        val.y = acc[i][1] + bvec[n + 1];
        val.z = acc[i][2] + bvec[n + 2];
        val.w = acc[i][3] + bvec[n + 3];
        if (qkv_layout) {
            const int b = m >> 10, l = m & 1023, d = n & 63;
            *(float4*)&C[(((b * 12 + h) << 10) + l) * 64 + d] = val;
        } else {
            *(float4*)&C[m * 768 + n] = val;
        }
    }
}

// ---------------------------------------------------------------------------
// Fused flash attention + spatial bias MLP.
// Grid: (L/64, B*H). Block 256 threads.
// Thread t: row r = t>>2 (of 64-row i-tile), lane-quad q = t&3.
// S columns per thread: c = 4*cc + q, cc=0..15 (interleaved -> no LDS bank clash)
// O columns per thread: d = q*16 .. q*16+15
// ---------------------------------------------------------------------------
__global__ __launch_bounds__(256) void attn_fused(
    const float* __restrict__ Q, const float* __restrict__ K,
    const float* __restrict__ V, const float* __restrict__ pos,
    const float* __restrict__ W1, const float* __restrict__ b1,
    const float* __restrict__ W2, const float* __restrict__ b2,
    float* __restrict__ AO) {
    __shared__ float Qs[64][68];
    __shared__ float Ks[64][68];
    __shared__ float Vs[64][68];
    __shared__ float Ps[64][68];
    __shared__ float posix[64], posiy[64], posjx[64], posjy[64];
    __shared__ float w1x[32], w1y[32], b1s[32], w2h[32];
    __shared__ float b2s;

    const int t  = threadIdx.x;
    const int bh = blockIdx.y;
    const int b  = bh / 12, h = bh % 12;
    const int i0 = blockIdx.x * 64;

    // ---- stage Q tile, pos_i, MLP params ----
#pragma unroll
    for (int e = 0; e < 4; ++e) {
        const int f = t + 256 * e;
        const int rr = f >> 4, kq = (f & 15) << 2;
        *(float4*)&Qs[rr][kq] = *(const float4*)&Q[((bh << 10) + i0 + rr) * 64 + kq];
    }
    if (t < 64) {
        float2 p = *(const float2*)&pos[((b << 10) + i0 + t) * 2];
        posix[t] = p.x;
        posiy[t] = p.y;
    }
    if (t < 32) {
        w1x[t] = W1[t];          // W1[0][u]
        w1y[t] = W1[32 + t];     // W1[1][u]
        b1s[t] = b1[t];
        w2h[t] = W2[t * 12 + h]; // W2[u][h]
    }
    if (t == 0) b2s = b2[h];

    const int r = t >> 2, q = t & 3;

    float mrun = -1e30f, lrun = 0.f;
    float4 o[4];
    o[0] = o[1] = o[2] = o[3] = make_float4(0.f, 0.f, 0.f, 0.f);

    for (int jt = 0; jt < 16; ++jt) {
        __syncthreads();  // previous tile's LDS reads done before overwrite
        const int j0 = jt << 6;
#pragma unroll
        for (int e = 0; e < 4; ++e) {
            const int f = t + 256 * e;
            const int rr = f >> 4, kq = (f & 15) << 2;
            *(float4*)&Ks[rr][kq] = *(const float4*)&K[((bh << 10) + j0 + rr) * 64 + kq];
            *(float4*)&Vs[rr][kq] = *(const float4*)&V[((bh << 10) + j0 + rr) * 64 + kq];
        }
        if (t < 64) {
            float2 p = *(const float2*)&pos[((b << 10) + j0 + t) * 2];
            posjx[t] = p.x;
            posjy[t] = p.y;
        }
        __syncthreads();

        // ---- S = Q . K^T (per-thread 16 interleaved columns) ----
        float s[16];
#pragma unroll
        for (int cc = 0; cc < 16; ++cc) s[cc] = 0.f;
#pragma unroll 4
        for (int k4 = 0; k4 < 16; ++k4) {
            float4 qv = *(const float4*)&Qs[r][k4 << 2];
#pragma unroll
            for (int cc = 0; cc < 16; ++cc) {
                const int c = (cc << 2) + q;
                float4 kv = *(const float4*)&Ks[c][k4 << 2];
                s[cc] = fmaf(qv.x, kv.x, s[cc]);
                s[cc] = fmaf(qv.y, kv.y, s[cc]);
                s[cc] = fmaf(qv.z, kv.z, s[cc]);
                s[cc] = fmaf(qv.w, kv.w, s[cc]);
            }
        }

        // ---- spatial bias MLP: bias = relu(delta@W1 + b1)@W2[:,h] + b2[h] ----
        const float px = posix[r], py = posiy[r];
        float dx[16], dy[16], bias[16];
#pragma unroll
        for (int cc = 0; cc < 16; ++cc) {
            const int c = (cc << 2) + q;
            dx[cc]   = px - posjx[c];
            dy[cc]   = py - posjy[c];
            bias[cc] = b2s;
        }
#pragma unroll 8
        for (int u = 0; u < 32; ++u) {
            const float a  = w1x[u];
            const float bu = w1y[u];
            const float cu = b1s[u];
            const float wo = w2h[u];
#pragma unroll
            for (int cc = 0; cc < 16; ++cc) {
                float hv = fmaf(dx[cc], a, fmaf(dy[cc], bu, cu));
                hv = fmaxf(hv, 0.f);
                bias[cc] = fmaf(hv, wo, bias[cc]);
            }
        }
#pragma unroll
        for (int cc = 0; cc < 16; ++cc) s[cc] = fmaf(s[cc], 0.125f, bias[cc]);

        // ---- online softmax (rows split over 4 lanes: shfl_xor 1,2) ----
        float mloc = s[0];
#pragma unroll
        for (int cc = 1; cc < 16; ++cc) mloc = fmaxf(mloc, s[cc]);
        mloc = fmaxf(mloc, __shfl_xor(mloc, 1));
        mloc = fmaxf(mloc, __shfl_xor(mloc, 2));
        const float mnew = fmaxf(mrun, mloc);
        const float corr = __expf(mrun - mnew);
        float p[16], psum = 0.f;
#pragma unroll
        for (int cc = 0; cc < 16; ++cc) {
            p[cc] = __expf(s[cc] - mnew);
            psum += p[cc];
        }
        psum += __shfl_xor(psum, 1);
        psum += __shfl_xor(psum, 2);
        lrun = lrun * corr + psum;
        mrun = mnew;

        // stash P in LDS (written & read by the same wave -> no barrier needed)
#pragma unroll
        for (int cc = 0; cc < 16; ++cc) Ps[r][(cc << 2) + q] = p[cc];

#pragma unroll
        for (int dv = 0; dv < 4; ++dv) {
            o[dv].x *= corr; o[dv].y *= corr;
            o[dv].z *= corr; o[dv].w *= corr;
        }

        // ---- O += P @ V  (thread owns row r, d-range q*16..q*16+15) ----
#pragma unroll 8
        for (int c = 0; c < 64; ++c) {
            const float pv = Ps[r][c];
#pragma unroll
            for (int dv = 0; dv < 4; ++dv) {
                float4 vv = *(const float4*)&Vs[c][(q << 4) + (dv << 2)];
                o[dv].x = fmaf(pv, vv.x, o[dv].x);
                o[dv].y = fmaf(pv, vv.y, o[dv].y);
                o[dv].z = fmaf(pv, vv.z, o[dv].z);
                o[dv].w = fmaf(pv, vv.w, o[dv].w);
            }
        }
    }

    // ---- epilogue: normalize, write AO[(b*1024+i)*768 + h*64 + d] ----
    const float inv = 1.f / lrun;
    float* dst = &AO[(((b << 10) + i0 + r)) * 768 + (h << 6) + (q << 4)];
#pragma unroll
    for (int dv = 0; dv < 4; ++dv) {
        float4 ov;
        ov.x = o[dv].x * inv;
        ov.y = o[dv].y * inv;
        ov.z = o[dv].z * inv;
        ov.w = o[dv].w * inv;
        *(float4*)&dst[dv << 2] = ov;
    }
}

extern "C" void kernel_launch(void* const* d_in, const int* in_sizes, int n_in,
                              void* d_out, int out_size, void* d_ws, size_t ws_size,
                              hipStream_t stream) {
    const float* x   = (const float*)d_in[0];
    const float* pos = (const float*)d_in[1];
    const float* Wq  = (const float*)d_in[2];
    const float* bq  = (const float*)d_in[3];
    const float* Wk  = (const float*)d_in[4];
    const float* bk  = (const float*)d_in[5];
    const float* Wv  = (const float*)d_in[6];
    const float* bv  = (const float*)d_in[7];
    const float* Wo  = (const float*)d_in[8];
    const float* bo  = (const float*)d_in[9];
    const float* W1  = (const float*)d_in[10];
    const float* b1  = (const float*)d_in[11];
    const float* W2  = (const float*)d_in[12];
    const float* b2  = (const float*)d_in[13];
    float* out = (float*)d_out;

    float* Qb  = (float*)d_ws;            // [48][1024][64]
    float* Kb  = Qb + 48 * 1024 * 64;
    float* Vb  = Kb + 48 * 1024 * 64;
    float* AOb = Vb + 48 * 1024 * 64;     // [4096][768]

    dim3 gg(12, 64);
    gemm768<<<gg, 256, 0, stream>>>(x, Wq, bq, Qb, 1);
    gemm768<<<gg, 256, 0, stream>>>(x, Wk, bk, Kb, 1);
    gemm768<<<gg, 256, 0, stream>>>(x, Wv, bv, Vb, 1);
    attn_fused<<<dim3(16, 48), 256, 0, stream>>>(Qb, Kb, Vb, pos, W1, b1, W2, b2, AOb);
    gemm768<<<gg, 256, 0, stream>>>(AOb, Wo, bo, out, 0);
}

// Round 2
// 638.424 us; speedup vs baseline: 1.3519x; 1.3519x over previous
//
#include <hip/hip_runtime.h>

// SpatialAwareAttention — fp32, bias-precompute + 4x4-blocked flash attention.
// B=4, L=1024, D=768, H=12, hd=64, BIAS_HIDDEN=32.
//
// Pipeline:
//   1) gemm768 x3 : Q/K/V = x@W + b, written as [B*H][L][64] into d_ws
//   2) bias_mlp   : bias[b][h][i][j] = relu(delta@W1+b1)@W2 + b2  (201 MB ws)
//   3) attn_fused : flash attention per (b,h,i-tile); loads precomputed bias
//   4) gemm768    : out = AO @ Wo + bo  -> d_out
//
// All fp32 on the vector ALU (no fp32-input MFMA on CDNA4).

// ---------------------------------------------------------------------------
// C[4096x768] = A[4096x768] @ W[768x768] + bvec
// qkv_layout==1: write C[m][n] to out[((b*12+h)*1024+l)*64+d]
// ---------------------------------------------------------------------------
__global__ __launch_bounds__(256) void gemm768(const float* __restrict__ A,
                                               const float* __restrict__ W,
                                               const float* __restrict__ bvec,
                                               float* __restrict__ C,
                                               int qkv_layout) {
    __shared__ float As[16][68];
    __shared__ float Bs[16][68];

    const int t  = threadIdx.x;
    const int tx = t & 15, ty = t >> 4;
    const int n0 = blockIdx.x * 64, m0 = blockIdx.y * 64;

    float acc[4][4];
#pragma unroll
    for (int i = 0; i < 4; ++i)
#pragma unroll
        for (int j = 0; j < 4; ++j) acc[i][j] = 0.f;

    const int ar  = t >> 2;
    const int akq = (t & 3) << 2;
    const int bkr = t >> 4;
    const int bnq = (t & 15) << 2;

    for (int k0 = 0; k0 < 768; k0 += 16) {
        __syncthreads();
        float4 av = *(const float4*)&A[(m0 + ar) * 768 + k0 + akq];
        As[akq + 0][ar] = av.x;
        As[akq + 1][ar] = av.y;
        As[akq + 2][ar] = av.z;
        As[akq + 3][ar] = av.w;
        *(float4*)&Bs[bkr][bnq] = *(const float4*)&W[(k0 + bkr) * 768 + n0 + bnq];
        __syncthreads();
#pragma unroll
        for (int kk = 0; kk < 16; ++kk) {
            float4 a4 = *(const float4*)&As[kk][ty << 2];
            float4 b4 = *(const float4*)&Bs[kk][tx << 2];
            float aa[4] = {a4.x, a4.y, a4.z, a4.w};
            float bb[4] = {b4.x, b4.y, b4.z, b4.w};
#pragma unroll
            for (int i = 0; i < 4; ++i)
#pragma unroll
                for (int j = 0; j < 4; ++j)
                    acc[i][j] = fmaf(aa[i], bb[j], acc[i][j]);
        }
    }

    const int h = n0 >> 6;
#pragma unroll
    for (int i = 0; i < 4; ++i) {
        const int m = m0 + (ty << 2) + i;
        const int n = n0 + (tx << 2);
        float4 val;
        val.x = acc[i][0] + bvec[n + 0];
        val.y = acc[i][1] + bvec[n + 1];
        val.z = acc[i][2] + bvec[n + 2];
        val.w = acc[i][3] + bvec[n + 3];
        if (qkv_layout) {
            const int b = m >> 10, l = m & 1023, d = n & 63;
            *(float4*)&C[(((b * 12 + h) << 10) + l) * 64 + d] = val;
        } else {
            *(float4*)&C[m * 768 + n] = val;
        }
    }
}

// ---------------------------------------------------------------------------
// bias[b][h][i][j] = relu(delta_ij @ W1 + b1) @ W2[:,h] + b2[h]
// Grid (1024 i, 4 b), 256 threads; thread handles j = t + 256*e, e=0..3.
// Hidden layer computed ONCE per (i,j) pair, shared across all 12 heads.
// ---------------------------------------------------------------------------
__global__ __launch_bounds__(256) void bias_mlp(const float* __restrict__ pos,
                                                const float* __restrict__ W1,
                                                const float* __restrict__ b1,
                                                const float* __restrict__ W2,
                                                const float* __restrict__ b2,
                                                float* __restrict__ Bias) {
    __shared__ float w1x[32], w1y[32], b1s[32], b2s[12];
    __shared__ float w2T[12][32];

    const int t = threadIdx.x;
    const int i = blockIdx.x;
    const int b = blockIdx.y;

    if (t < 32) { w1x[t] = W1[t]; w1y[t] = W1[32 + t]; b1s[t] = b1[t]; }
    if (t >= 32 && t < 44) b2s[t - 32] = b2[t - 32];
    for (int v = t; v < 384; v += 256) {
        const int u = v / 12, hh = v - u * 12;
        w2T[hh][u] = W2[v];
    }
    __syncthreads();

    const float2 pi2 = *(const float2*)&pos[((b << 10) + i) << 1];
    float dx[4], dy[4];
#pragma unroll
    for (int e = 0; e < 4; ++e) {
        float2 pj = *(const float2*)&pos[((b << 10) + t + 256 * e) << 1];
        dx[e] = pi2.x - pj.x;
        dy[e] = pi2.y - pj.y;
    }

    float acc[4][12];
#pragma unroll
    for (int e = 0; e < 4; ++e)
#pragma unroll
        for (int h = 0; h < 12; ++h) acc[e][h] = b2s[h];

#pragma unroll
    for (int u4 = 0; u4 < 8; ++u4) {
        const float4 ax = *(const float4*)&w1x[u4 << 2];
        const float4 ay = *(const float4*)&w1y[u4 << 2];
        const float4 ab = *(const float4*)&b1s[u4 << 2];
        float4 hv[4];
#pragma unroll
        for (int e = 0; e < 4; ++e) {
            hv[e].x = fmaxf(fmaf(dx[e], ax.x, fmaf(dy[e], ay.x, ab.x)), 0.f);
            hv[e].y = fmaxf(fmaf(dx[e], ax.y, fmaf(dy[e], ay.y, ab.y)), 0.f);
            hv[e].z = fmaxf(fmaf(dx[e], ax.z, fmaf(dy[e], ay.z, ab.z)), 0.f);
            hv[e].w = fmaxf(fmaf(dx[e], ax.w, fmaf(dy[e], ay.w, ab.w)), 0.f);
        }
#pragma unroll
        for (int h = 0; h < 12; ++h) {
            const float4 wv = *(const float4*)&w2T[h][u4 << 2];
#pragma unroll
            for (int e = 0; e < 4; ++e)
                acc[e][h] = fmaf(hv[e].x, wv.x,
                            fmaf(hv[e].y, wv.y,
                            fmaf(hv[e].z, wv.z,
                            fmaf(hv[e].w, wv.w, acc[e][h]))));
        }
    }

    const size_t base = ((size_t)(b * 12)) << 20;
#pragma unroll
    for (int h = 0; h < 12; ++h) {
        const size_t off = base + (((size_t)h) << 20) + (((size_t)i) << 10);
#pragma unroll
        for (int e = 0; e < 4; ++e) Bias[off + t + 256 * e] = acc[e][h];
    }
}

// ---------------------------------------------------------------------------
// Flash attention, 4x4 register blocking.
// Block 256 thr = 4 waves; wave w owns rows [w*16, w*16+16).
// lane: q=lane&3, rr=(lane>>2)&3, g=lane>>4.
//   rows  = w*16 + rr + 4*i   (i=0..3)
//   cols  = (g*4+q) + 16*cc   (cc=0..3)   [bank-spread for Ks reads]
//   O d   = (g*4+q)*4 .. +3
// P is staged through the retired Ks tile (barrier first), read same-wave.
// PRE=1: bias loaded from precomputed tensor; PRE=0: in-kernel MLP fallback.
// ---------------------------------------------------------------------------
template <int PRE>
__global__ __launch_bounds__(256, 3) void attn_fused(
    const float* __restrict__ Q, const float* __restrict__ K,
    const float* __restrict__ V, const float* __restrict__ BiasT,
    const float* __restrict__ pos, const float* __restrict__ W1,
    const float* __restrict__ b1, const float* __restrict__ W2,
    const float* __restrict__ b2, float* __restrict__ AO) {
    __shared__ float Qs[64][68];
    __shared__ float Ks[64][68];   // K tile, then reused to hold P
    __shared__ float Vs[64][68];
    __shared__ float posix[64], posiy[64], posjx[64], posjy[64];
    __shared__ float w1x[32], w1y[32], b1s[32], w2h[32];
    __shared__ float b2v[1];

    const int t    = threadIdx.x;
    const int bh   = blockIdx.y;
    const int b    = bh / 12, h = bh - b * 12;
    const int i0   = blockIdx.x << 6;
    const int w    = t >> 6;
    const int lane = t & 63;
    const int q    = lane & 3;
    const int rr   = (lane >> 2) & 3;
    const int g    = lane >> 4;
    const int colb = (g << 2) + q;      // 0..15
    const int rowb = (w << 4) + rr;     // row base within i-tile
    const int d0   = colb << 2;         // output d quad

    // ---- stage Q tile (+ fallback params) ----
#pragma unroll
    for (int e = 0; e < 4; ++e) {
        const int f = t + 256 * e;
        const int r2 = f >> 4, kq = (f & 15) << 2;
        *(float4*)&Qs[r2][kq] = *(const float4*)&Q[(((bh << 10) + i0 + r2) << 6) + kq];
    }
    if constexpr (PRE == 0) {
        if (t < 64) {
            float2 p = *(const float2*)&pos[((b << 10) + i0 + t) << 1];
            posix[t] = p.x;
            posiy[t] = p.y;
        }
        if (t < 32) {
            w1x[t] = W1[t];
            w1y[t] = W1[32 + t];
            b1s[t] = b1[t];
            w2h[t] = W2[t * 12 + h];
        }
        if (t == 64) b2v[0] = b2[h];
    }

    float m_[4], l_[4];
    float4 o_[4];
#pragma unroll
    for (int i = 0; i < 4; ++i) {
        m_[i] = -1e30f;
        l_[i] = 0.f;
        o_[i] = make_float4(0.f, 0.f, 0.f, 0.f);
    }

    for (int jt = 0; jt < 16; ++jt) {
        const int j0 = jt << 6;
        float bias[4][4];
        if constexpr (PRE == 1) {
            const float* bp = BiasT + (((size_t)bh) << 20);
#pragma unroll
            for (int i = 0; i < 4; ++i) {
                const float* rowp = bp + (((size_t)(i0 + rowb + (i << 2))) << 10) + j0 + colb;
#pragma unroll
                for (int cc = 0; cc < 4; ++cc) bias[i][cc] = rowp[cc << 4];
            }
        }
        __syncthreads();  // prior tile's P/V reads complete before restage
#pragma unroll
        for (int e = 0; e < 4; ++e) {
            const int f = t + 256 * e;
            const int r2 = f >> 4, kq = (f & 15) << 2;
            *(float4*)&Ks[r2][kq] = *(const float4*)&K[(((bh << 10) + j0 + r2) << 6) + kq];
            *(float4*)&Vs[r2][kq] = *(const float4*)&V[(((bh << 10) + j0 + r2) << 6) + kq];
        }
        if constexpr (PRE == 0) {
            if (t < 64) {
                float2 p = *(const float2*)&pos[((b << 10) + j0 + t) << 1];
                posjx[t] = p.x;
                posjy[t] = p.y;
            }
        }
        __syncthreads();

        // ---- S = Q . K^T ----
        float s_[4][4];
#pragma unroll
        for (int i = 0; i < 4; ++i)
#pragma unroll
            for (int cc = 0; cc < 4; ++cc) s_[i][cc] = 0.f;
#pragma unroll 4
        for (int k4 = 0; k4 < 16; ++k4) {
            float4 qv[4];
#pragma unroll
            for (int i = 0; i < 4; ++i)
                qv[i] = *(const float4*)&Qs[rowb + (i << 2)][k4 << 2];
#pragma unroll
            for (int cc = 0; cc < 4; ++cc) {
                const float4 kv = *(const float4*)&Ks[colb + (cc << 4)][k4 << 2];
#pragma unroll
                for (int i = 0; i < 4; ++i) {
                    s_[i][cc] = fmaf(qv[i].x, kv.x, s_[i][cc]);
                    s_[i][cc] = fmaf(qv[i].y, kv.y, s_[i][cc]);
                    s_[i][cc] = fmaf(qv[i].z, kv.z, s_[i][cc]);
                    s_[i][cc] = fmaf(qv[i].w, kv.w, s_[i][cc]);
                }
            }
        }

        if constexpr (PRE == 0) {
            float dxv[4][4], dyv[4][4];
#pragma unroll
            for (int i = 0; i < 4; ++i) {
                const float px = posix[rowb + (i << 2)];
                const float py = posiy[rowb + (i << 2)];
#pragma unroll
                for (int cc = 0; cc < 4; ++cc) {
                    const int c = colb + (cc << 4);
                    dxv[i][cc]  = px - posjx[c];
                    dyv[i][cc]  = py - posjy[c];
                    bias[i][cc] = b2v[0];
                }
            }
#pragma unroll 8
            for (int u = 0; u < 32; ++u) {
                const float a = w1x[u], bu = w1y[u], cu = b1s[u], wo = w2h[u];
#pragma unroll
                for (int i = 0; i < 4; ++i)
#pragma unroll
                    for (int cc = 0; cc < 4; ++cc) {
                        float hv = fmaf(dxv[i][cc], a, fmaf(dyv[i][cc], bu, cu));
                        bias[i][cc] = fmaf(fmaxf(hv, 0.f), wo, bias[i][cc]);
                    }
            }
        }

#pragma unroll
        for (int i = 0; i < 4; ++i)
#pragma unroll
            for (int cc = 0; cc < 4; ++cc)
                s_[i][cc] = fmaf(s_[i][cc], 0.125f, bias[i][cc]);

        // ---- online softmax (row spread over lanes q:1,2 and g:16,32) ----
        float corr[4];
#pragma unroll
        for (int i = 0; i < 4; ++i) {
            float mx = fmaxf(fmaxf(s_[i][0], s_[i][1]), fmaxf(s_[i][2], s_[i][3]));
            mx = fmaxf(mx, __shfl_xor(mx, 1));
            mx = fmaxf(mx, __shfl_xor(mx, 2));
            mx = fmaxf(mx, __shfl_xor(mx, 16));
            mx = fmaxf(mx, __shfl_xor(mx, 32));
            const float mn = fmaxf(m_[i], mx);
            corr[i] = __expf(m_[i] - mn);
            m_[i] = mn;
            float ps = 0.f;
#pragma unroll
            for (int cc = 0; cc < 4; ++cc) {
                s_[i][cc] = __expf(s_[i][cc] - mn);
                ps += s_[i][cc];
            }
            ps += __shfl_xor(ps, 1);
            ps += __shfl_xor(ps, 2);
            ps += __shfl_xor(ps, 16);
            ps += __shfl_xor(ps, 32);
            l_[i] = fmaf(l_[i], corr[i], ps);
            o_[i].x *= corr[i];
            o_[i].y *= corr[i];
            o_[i].z *= corr[i];
            o_[i].w *= corr[i];
        }

        __syncthreads();  // all waves done reading K values from Ks
#pragma unroll
        for (int i = 0; i < 4; ++i)
#pragma unroll
            for (int cc = 0; cc < 4; ++cc)
                Ks[rowb + (i << 2)][colb + (cc << 4)] = s_[i][cc];

        // ---- O += P @ V (P read same-wave from Ks region) ----
#pragma unroll 4
        for (int c4 = 0; c4 < 16; ++c4) {
            float4 pv[4];
#pragma unroll
            for (int i = 0; i < 4; ++i)
                pv[i] = *(const float4*)&Ks[rowb + (i << 2)][c4 << 2];
            float4 vv[4];
#pragma unroll
            for (int cc2 = 0; cc2 < 4; ++cc2)
                vv[cc2] = *(const float4*)&Vs[(c4 << 2) + cc2][d0];
#pragma unroll
            for (int i = 0; i < 4; ++i) {
                const float* pf = (const float*)&pv[i];
#pragma unroll
                for (int cc2 = 0; cc2 < 4; ++cc2) {
                    o_[i].x = fmaf(pf[cc2], vv[cc2].x, o_[i].x);
                    o_[i].y = fmaf(pf[cc2], vv[cc2].y, o_[i].y);
                    o_[i].z = fmaf(pf[cc2], vv[cc2].z, o_[i].z);
                    o_[i].w = fmaf(pf[cc2], vv[cc2].w, o_[i].w);
                }
            }
        }
    }

    // ---- epilogue ----
#pragma unroll
    for (int i = 0; i < 4; ++i) {
        const float inv = 1.f / l_[i];
        float4 ov;
        ov.x = o_[i].x * inv;
        ov.y = o_[i].y * inv;
        ov.z = o_[i].z * inv;
        ov.w = o_[i].w * inv;
        *(float4*)&AO[(size_t)((b << 10) + i0 + rowb + (i << 2)) * 768 + (h << 6) + d0] = ov;
    }
}

extern "C" void kernel_launch(void* const* d_in, const int* in_sizes, int n_in,
                              void* d_out, int out_size, void* d_ws, size_t ws_size,
                              hipStream_t stream) {
    const float* x   = (const float*)d_in[0];
    const float* pos = (const float*)d_in[1];
    const float* Wq  = (const float*)d_in[2];
    const float* bq  = (const float*)d_in[3];
    const float* Wk  = (const float*)d_in[4];
    const float* bk  = (const float*)d_in[5];
    const float* Wv  = (const float*)d_in[6];
    const float* bv  = (const float*)d_in[7];
    const float* Wo  = (const float*)d_in[8];
    const float* bo  = (const float*)d_in[9];
    const float* W1  = (const float*)d_in[10];
    const float* b1  = (const float*)d_in[11];
    const float* W2  = (const float*)d_in[12];
    const float* b2  = (const float*)d_in[13];
    float* out = (float*)d_out;

    float* Qb    = (float*)d_ws;           // [48][1024][64]
    float* Kb    = Qb + 3145728;
    float* Vb    = Kb + 3145728;
    float* AOb   = Vb + 3145728;           // [4096][768]
    float* Biasb = AOb + 3145728;          // [48][1024][1024]

    const size_t need = (size_t)(4 * 3145728 + 48 * 1048576) * 4;  // 251,658,240 B
    const bool pre = ws_size >= need;

    dim3 gg(12, 64);
    gemm768<<<gg, 256, 0, stream>>>(x, Wq, bq, Qb, 1);
    gemm768<<<gg, 256, 0, stream>>>(x, Wk, bk, Kb, 1);
    gemm768<<<gg, 256, 0, stream>>>(x, Wv, bv, Vb, 1);
    if (pre) {
        bias_mlp<<<dim3(1024, 4), 256, 0, stream>>>(pos, W1, b1, W2, b2, Biasb);
        attn_fused<1><<<dim3(16, 48), 256, 0, stream>>>(Qb, Kb, Vb, Biasb, pos, W1, b1,
                                                        W2, b2, AOb);
    } else {
        attn_fused<0><<<dim3(16, 48), 256, 0, stream>>>(Qb, Kb, Vb, nullptr, pos, W1, b1,
                                                        W2, b2, AOb);
    }
    gemm768<<<gg, 256, 0, stream>>>(AOb, Wo, bo, out, 0);
}

// Round 4
// 489.253 us; speedup vs baseline: 1.7640x; 1.3049x over previous
//
#include <hip/hip_runtime.h>
#include <hip/hip_fp16.h>

// SpatialAwareAttention — round 3 resubmit: bf16x3-split MFMA GEMMs + fp16 bias.
// B=4, L=1024, D=768, H=12, hd=64, BIAS_HIDDEN=32.
//
// Pipeline:
//   1) split_hi_lo : x -> A2[4096][2304] bf16  ([Ah|Ah|Al] K-blocks)
//   2) split_wT x3 : Wq/Wk/Wv -> W2t[2304 n][2304 k] bf16 ([Wh;Wl;Wh], transposed)
//   3) mfma_gemm<1>: QKV = A2 @ W2t^T (one fused GEMM, MFMA bf16, fp32 accum)
//   4) bias_mlp    : bias[b][h][i][j] fp16 (hidden layer computed once per pair)
//   5) attn_fused  : fp32 flash attention + precomputed bias
//   6) split_hi_lo : AO -> A2 ; split_wT: Wo -> W2t
//   7) mfma_gemm<0>: out = AO2 @ W2ot^T + bo
//
// bf16x3: X = Xh + Xl keeps ~16 mantissa bits; dropped Xl*Wl term is ~2^-34.

typedef unsigned short ushort_t;
typedef unsigned int uint_t;
typedef __attribute__((ext_vector_type(8))) short bf16x8;
typedef __attribute__((ext_vector_type(4))) float f32x4;

__device__ __forceinline__ ushort_t f2b(float f) {  // fp32 -> bf16 (RNE)
    union { float f; uint_t u; } v;
    v.f = f;
    uint_t r = v.u + 0x7fffu + ((v.u >> 16) & 1u);
    return (ushort_t)(r >> 16);
}
__device__ __forceinline__ float b2f(ushort_t b) {
    union { uint_t u; float f; } v;
    v.u = ((uint_t)b) << 16;
    return v.f;
}

__device__ __forceinline__ void gload16(const void* g, void* l) {
    __builtin_amdgcn_global_load_lds(
        (const __attribute__((address_space(1))) unsigned int*)g,
        (__attribute__((address_space(3))) unsigned int*)l, 16, 0, 0);
}

// ---------------------------------------------------------------------------
// X[4096][768] fp32 -> X2[4096][2304] bf16 as [hi | hi | lo]
// ---------------------------------------------------------------------------
__global__ __launch_bounds__(256) void split_hi_lo(const float* __restrict__ X,
                                                   ushort_t* __restrict__ X2) {
    const int idx = blockIdx.x * 256 + threadIdx.x;  // over 786432 float4s
    const int m = idx / 192, k4 = (idx - m * 192) * 4;
    float4 v = *(const float4*)&X[(size_t)m * 768 + k4];
    ushort4 hi, lo;
    hi.x = f2b(v.x); lo.x = f2b(v.x - b2f(hi.x));
    hi.y = f2b(v.y); lo.y = f2b(v.y - b2f(hi.y));
    hi.z = f2b(v.z); lo.z = f2b(v.z - b2f(hi.z));
    hi.w = f2b(v.w); lo.w = f2b(v.w - b2f(hi.w));
    ushort_t* row = X2 + (size_t)m * 2304;
    *(ushort4*)&row[k4]        = hi;
    *(ushort4*)&row[768 + k4]  = hi;
    *(ushort4*)&row[1536 + k4] = lo;
}

// ---------------------------------------------------------------------------
// W[768 k][768 n] fp32 -> Wt[n_base+n][2304 k] bf16 as k-blocks [hi ; lo ; hi]
// (transposed so GEMM B-tile staging is a linear copy). Grid (12,12).
// ---------------------------------------------------------------------------
__global__ __launch_bounds__(256) void split_wT(const float* __restrict__ W,
                                                ushort_t* __restrict__ Wt,
                                                int n_base) {
    __shared__ float Ws[64][65];
    const int t = threadIdx.x;
    const int rr0 = blockIdx.x * 64, nn0 = blockIdx.y * 64;
    const int c = t & 63, r4 = t >> 6;
#pragma unroll
    for (int e = 0; e < 16; ++e) {
        const int r = r4 + e * 4;
        Ws[r][c] = W[(size_t)(rr0 + r) * 768 + nn0 + c];
    }
    __syncthreads();
#pragma unroll
    for (int e = 0; e < 16; ++e) {
        const int nloc = r4 + e * 4;
        const float v = Ws[c][nloc];
        const ushort_t h = f2b(v);
        const ushort_t l = f2b(v - b2f(h));
        ushort_t* rowp = Wt + (size_t)(n_base + nn0 + nloc) * 2304 + rr0 + c;
        rowp[0]    = h;
        rowp[768]  = l;
        rowp[1536] = h;
    }
}

// ---------------------------------------------------------------------------
// C[4096 x N] = A2[4096][2304] @ Bt[N][2304]^T, MFMA bf16 16x16x32, fp32 acc.
// 128x128 tile, BK=64, 4 waves (2x2 quadrants of 64x64), single-buffered LDS.
// LDS XOR swizzle slot^=(row&7) applied on the pre-swizzled global SOURCE of
// global_load_lds (linear dest) and on the ds_read address (rule #21).
// QKV=1: N=2304 fused [Q|K|V], scatter epilogue to [B*H][L][64] buffers.
// QKV=0: N=768 plain row-major epilogue to C0 (+bias0).
// ---------------------------------------------------------------------------
template <int QKV>
__global__ __launch_bounds__(256) void mfma_gemm(
    const ushort_t* __restrict__ A2, const ushort_t* __restrict__ Bt,
    const float* __restrict__ bias0, const float* __restrict__ bias1,
    const float* __restrict__ bias2, float* __restrict__ C0,
    float* __restrict__ C1, float* __restrict__ C2) {
    __shared__ ushort_t As[128 * 64];
    __shared__ ushort_t Bs[128 * 64];

    const int t = threadIdx.x;
    const int w = t >> 6, lane = t & 63;
    const int n0 = blockIdx.x * 128, m0 = blockIdx.y * 128;
    const int wr = (w >> 1) * 64, wc = (w & 1) * 64;

    f32x4 acc[4][4];
#pragma unroll
    for (int i = 0; i < 4; ++i)
#pragma unroll
        for (int j = 0; j < 4; ++j) acc[i][j] = (f32x4){0.f, 0.f, 0.f, 0.f};

    // staging geometry: d16 = it*256 + t ; row = d16>>3 ; slot = d16&7
    const int srow = t >> 3;          // row advance per it: +32
    const int sslot = t & 7;

    for (int k0 = 0; k0 < 2304; k0 += 64) {
        __syncthreads();
#pragma unroll
        for (int it = 0; it < 4; ++it) {
            const int row = srow + it * 32;
            const int kk = k0 + (((sslot ^ (row & 7)) << 3));
            char* dstA = (char*)As + it * 4096 + w * 1024;
            char* dstB = (char*)Bs + it * 4096 + w * 1024;
            gload16(A2 + (size_t)(m0 + row) * 2304 + kk, dstA);
            gload16(Bt + (size_t)(n0 + row) * 2304 + kk, dstB);
        }
        __syncthreads();

#pragma unroll
        for (int kk = 0; kk < 2; ++kk) {
            bf16x8 a[4], b[4];
#pragma unroll
            for (int i = 0; i < 4; ++i) {
                const int ra = wr + i * 16 + (lane & 15);
                const int sa = ((kk << 2) + (lane >> 4)) ^ (ra & 7);
                a[i] = *(const bf16x8*)((const char*)As + ra * 128 + sa * 16);
                const int rb = wc + i * 16 + (lane & 15);
                const int sb = ((kk << 2) + (lane >> 4)) ^ (rb & 7);
                b[i] = *(const bf16x8*)((const char*)Bs + rb * 128 + sb * 16);
            }
#pragma unroll
            for (int i = 0; i < 4; ++i)
#pragma unroll
                for (int j = 0; j < 4; ++j)
                    acc[i][j] = __builtin_amdgcn_mfma_f32_16x16x32_bf16(
                        a[i], b[j], acc[i][j], 0, 0, 0);
        }
    }

    // epilogue: C/D layout col = lane&15, row = (lane>>4)*4 + reg
    const int cl = lane & 15, rg = (lane >> 4) * 4;
#pragma unroll
    for (int i = 0; i < 4; ++i)
#pragma unroll
        for (int j = 0; j < 4; ++j) {
            const int gc = n0 + wc + j * 16 + cl;
#pragma unroll
            for (int r = 0; r < 4; ++r) {
                const int gr = m0 + wr + i * 16 + rg + r;
                const float val = acc[i][j][r];
                if constexpr (QKV) {
                    const int which = gc / 768;
                    const int cw = gc - which * 768;
                    const float* bb = which == 0 ? bias0 : (which == 1 ? bias1 : bias2);
                    float* dst = which == 0 ? C0 : (which == 1 ? C1 : C2);
                    const int h = cw >> 6, d = cw & 63;
                    const int b = gr >> 10, l = gr & 1023;
                    dst[(size_t)((((b * 12 + h) << 10) + l)) * 64 + d] = val + bb[cw];
                } else {
                    C0[(size_t)gr * 768 + gc] = val + bias0[gc];
                }
            }
        }
}

// ---------------------------------------------------------------------------
// bias[b][h][i][j] = relu(delta_ij @ W1 + b1) @ W2[:,h] + b2[h]  -> fp16
// ---------------------------------------------------------------------------
__global__ __launch_bounds__(256) void bias_mlp(const float* __restrict__ pos,
                                                const float* __restrict__ W1,
                                                const float* __restrict__ b1,
                                                const float* __restrict__ W2,
                                                const float* __restrict__ b2,
                                                __half* __restrict__ Bias) {
    __shared__ float w1x[32], w1y[32], b1s[32], b2s[12];
    __shared__ float w2T[12][32];

    const int t = threadIdx.x;
    const int i = blockIdx.x;
    const int b = blockIdx.y;

    if (t < 32) { w1x[t] = W1[t]; w1y[t] = W1[32 + t]; b1s[t] = b1[t]; }
    if (t >= 32 && t < 44) b2s[t - 32] = b2[t - 32];
    for (int v = t; v < 384; v += 256) {
        const int u = v / 12, hh = v - u * 12;
        w2T[hh][u] = W2[v];
    }
    __syncthreads();

    const float2 pi2 = *(const float2*)&pos[((b << 10) + i) << 1];
    float dx[4], dy[4];
#pragma unroll
    for (int e = 0; e < 4; ++e) {
        float2 pj = *(const float2*)&pos[((b << 10) + t + 256 * e) << 1];
        dx[e] = pi2.x - pj.x;
        dy[e] = pi2.y - pj.y;
    }

    float acc[4][12];
#pragma unroll
    for (int e = 0; e < 4; ++e)
#pragma unroll
        for (int h = 0; h < 12; ++h) acc[e][h] = b2s[h];

#pragma unroll
    for (int u4 = 0; u4 < 8; ++u4) {
        const float4 ax = *(const float4*)&w1x[u4 << 2];
        const float4 ay = *(const float4*)&w1y[u4 << 2];
        const float4 ab = *(const float4*)&b1s[u4 << 2];
        float4 hv[4];
#pragma unroll
        for (int e = 0; e < 4; ++e) {
            hv[e].x = fmaxf(fmaf(dx[e], ax.x, fmaf(dy[e], ay.x, ab.x)), 0.f);
            hv[e].y = fmaxf(fmaf(dx[e], ax.y, fmaf(dy[e], ay.y, ab.y)), 0.f);
            hv[e].z = fmaxf(fmaf(dx[e], ax.z, fmaf(dy[e], ay.z, ab.z)), 0.f);
            hv[e].w = fmaxf(fmaf(dx[e], ax.w, fmaf(dy[e], ay.w, ab.w)), 0.f);
        }
#pragma unroll
        for (int h = 0; h < 12; ++h) {
            const float4 wv = *(const float4*)&w2T[h][u4 << 2];
#pragma unroll
            for (int e = 0; e < 4; ++e)
                acc[e][h] = fmaf(hv[e].x, wv.x,
                            fmaf(hv[e].y, wv.y,
                            fmaf(hv[e].z, wv.z,
                            fmaf(hv[e].w, wv.w, acc[e][h]))));
        }
    }

    const size_t base = ((size_t)(b * 12)) << 20;
#pragma unroll
    for (int h = 0; h < 12; ++h) {
        const size_t off = base + (((size_t)h) << 20) + (((size_t)i) << 10);
#pragma unroll
        for (int e = 0; e < 4; ++e) Bias[off + t + 256 * e] = __float2half(acc[e][h]);
    }
}

// ---------------------------------------------------------------------------
// Flash attention, 4x4 register blocking (fp32 compute; fp16 bias loads).
// ---------------------------------------------------------------------------
__global__ __launch_bounds__(256, 3) void attn_fused(
    const float* __restrict__ Q, const float* __restrict__ K,
    const float* __restrict__ V, const __half* __restrict__ BiasT,
    float* __restrict__ AO) {
    __shared__ float Qs[64][68];
    __shared__ float Ks[64][68];   // K tile, then reused to hold P
    __shared__ float Vs[64][68];

    const int t    = threadIdx.x;
    const int bh   = blockIdx.y;
    const int b    = bh / 12, h = bh - b * 12;
    const int i0   = blockIdx.x << 6;
    const int w    = t >> 6;
    const int lane = t & 63;
    const int q    = lane & 3;
    const int rr   = (lane >> 2) & 3;
    const int g    = lane >> 4;
    const int colb = (g << 2) + q;
    const int rowb = (w << 4) + rr;
    const int d0   = colb << 2;

#pragma unroll
    for (int e = 0; e < 4; ++e) {
        const int f = t + 256 * e;
        const int r2 = f >> 4, kq = (f & 15) << 2;
        *(float4*)&Qs[r2][kq] = *(const float4*)&Q[(((bh << 10) + i0 + r2) << 6) + kq];
    }

    float m_[4], l_[4];
    float4 o_[4];
#pragma unroll
    for (int i = 0; i < 4; ++i) {
        m_[i] = -1e30f;
        l_[i] = 0.f;
        o_[i] = make_float4(0.f, 0.f, 0.f, 0.f);
    }

    for (int jt = 0; jt < 16; ++jt) {
        const int j0 = jt << 6;
        float bias[4][4];
        {
            const __half* bp = BiasT + (((size_t)bh) << 20);
#pragma unroll
            for (int i = 0; i < 4; ++i) {
                const __half* rowp =
                    bp + (((size_t)(i0 + rowb + (i << 2))) << 10) + j0 + colb;
#pragma unroll
                for (int cc = 0; cc < 4; ++cc) bias[i][cc] = __half2float(rowp[cc << 4]);
            }
        }
        __syncthreads();
#pragma unroll
        for (int e = 0; e < 4; ++e) {
            const int f = t + 256 * e;
            const int r2 = f >> 4, kq = (f & 15) << 2;
            *(float4*)&Ks[r2][kq] = *(const float4*)&K[(((bh << 10) + j0 + r2) << 6) + kq];
            *(float4*)&Vs[r2][kq] = *(const float4*)&V[(((bh << 10) + j0 + r2) << 6) + kq];
        }
        __syncthreads();

        // ---- S = Q . K^T ----
        float s_[4][4];
#pragma unroll
        for (int i = 0; i < 4; ++i)
#pragma unroll
            for (int cc = 0; cc < 4; ++cc) s_[i][cc] = 0.f;
#pragma unroll 4
        for (int k4 = 0; k4 < 16; ++k4) {
            float4 qv[4];
#pragma unroll
            for (int i = 0; i < 4; ++i)
                qv[i] = *(const float4*)&Qs[rowb + (i << 2)][k4 << 2];
#pragma unroll
            for (int cc = 0; cc < 4; ++cc) {
                const float4 kv = *(const float4*)&Ks[colb + (cc << 4)][k4 << 2];
#pragma unroll
                for (int i = 0; i < 4; ++i) {
                    s_[i][cc] = fmaf(qv[i].x, kv.x, s_[i][cc]);
                    s_[i][cc] = fmaf(qv[i].y, kv.y, s_[i][cc]);
                    s_[i][cc] = fmaf(qv[i].z, kv.z, s_[i][cc]);
                    s_[i][cc] = fmaf(qv[i].w, kv.w, s_[i][cc]);
                }
            }
        }

#pragma unroll
        for (int i = 0; i < 4; ++i)
#pragma unroll
            for (int cc = 0; cc < 4; ++cc)
                s_[i][cc] = fmaf(s_[i][cc], 0.125f, bias[i][cc]);

        // ---- online softmax ----
        float corr[4];
#pragma unroll
        for (int i = 0; i < 4; ++i) {
            float mx = fmaxf(fmaxf(s_[i][0], s_[i][1]), fmaxf(s_[i][2], s_[i][3]));
            mx = fmaxf(mx, __shfl_xor(mx, 1));
            mx = fmaxf(mx, __shfl_xor(mx, 2));
            mx = fmaxf(mx, __shfl_xor(mx, 16));
            mx = fmaxf(mx, __shfl_xor(mx, 32));
            const float mn = fmaxf(m_[i], mx);
            corr[i] = __expf(m_[i] - mn);
            m_[i] = mn;
            float ps = 0.f;
#pragma unroll
            for (int cc = 0; cc < 4; ++cc) {
                s_[i][cc] = __expf(s_[i][cc] - mn);
                ps += s_[i][cc];
            }
            ps += __shfl_xor(ps, 1);
            ps += __shfl_xor(ps, 2);
            ps += __shfl_xor(ps, 16);
            ps += __shfl_xor(ps, 32);
            l_[i] = fmaf(l_[i], corr[i], ps);
            o_[i].x *= corr[i];
            o_[i].y *= corr[i];
            o_[i].z *= corr[i];
            o_[i].w *= corr[i];
        }

        __syncthreads();  // all waves done reading K values from Ks
#pragma unroll
        for (int i = 0; i < 4; ++i)
#pragma unroll
            for (int cc = 0; cc < 4; ++cc)
                Ks[rowb + (i << 2)][colb + (cc << 4)] = s_[i][cc];

        // ---- O += P @ V ----
#pragma unroll 4
        for (int c4 = 0; c4 < 16; ++c4) {
            float4 pv[4];
#pragma unroll
            for (int i = 0; i < 4; ++i)
                pv[i] = *(const float4*)&Ks[rowb + (i << 2)][c4 << 2];
            float4 vv[4];
#pragma unroll
            for (int cc2 = 0; cc2 < 4; ++cc2)
                vv[cc2] = *(const float4*)&Vs[(c4 << 2) + cc2][d0];
#pragma unroll
            for (int i = 0; i < 4; ++i) {
                const float* pf = (const float*)&pv[i];
#pragma unroll
                for (int cc2 = 0; cc2 < 4; ++cc2) {
                    o_[i].x = fmaf(pf[cc2], vv[cc2].x, o_[i].x);
                    o_[i].y = fmaf(pf[cc2], vv[cc2].y, o_[i].y);
                    o_[i].z = fmaf(pf[cc2], vv[cc2].z, o_[i].z);
                    o_[i].w = fmaf(pf[cc2], vv[cc2].w, o_[i].w);
                }
            }
        }
    }

#pragma unroll
    for (int i = 0; i < 4; ++i) {
        const float inv = 1.f / l_[i];
        float4 ov;
        ov.x = o_[i].x * inv;
        ov.y = o_[i].y * inv;
        ov.z = o_[i].z * inv;
        ov.w = o_[i].w * inv;
        *(float4*)&AO[(size_t)((b << 10) + i0 + rowb + (i << 2)) * 768 + (h << 6) + d0] = ov;
    }
}

extern "C" void kernel_launch(void* const* d_in, const int* in_sizes, int n_in,
                              void* d_out, int out_size, void* d_ws, size_t ws_size,
                              hipStream_t stream) {
    const float* x   = (const float*)d_in[0];
    const float* pos = (const float*)d_in[1];
    const float* Wq  = (const float*)d_in[2];
    const float* bq  = (const float*)d_in[3];
    const float* Wk  = (const float*)d_in[4];
    const float* bk  = (const float*)d_in[5];
    const float* Wv  = (const float*)d_in[6];
    const float* bv  = (const float*)d_in[7];
    const float* Wo  = (const float*)d_in[8];
    const float* bo  = (const float*)d_in[9];
    const float* W1  = (const float*)d_in[10];
    const float* b1  = (const float*)d_in[11];
    const float* W2  = (const float*)d_in[12];
    const float* b2  = (const float*)d_in[13];
    float* out = (float*)d_out;

    // ws layout (bytes): Q/K/V/AO fp32 (4 x 12.58MB) | BiasH fp16 (100.7MB)
    //                    | A2 bf16 (18.9MB, reused for AO2) | W2 bf16 (10.6MB)
    float* Qb  = (float*)d_ws;
    float* Kb  = Qb + 3145728;
    float* Vb  = Kb + 3145728;
    float* AOb = Vb + 3145728;
    __half* BiasH = (__half*)(AOb + 3145728);     // 50331648 halfs
    ushort_t* A2  = (ushort_t*)(BiasH + 50331648); // 9437184 ush
    ushort_t* W2b = A2 + 9437184;                  // 5308416 ush

    // 1) split x ; 2) split QKV weights (transposed)
    split_hi_lo<<<3072, 256, 0, stream>>>(x, A2);
    split_wT<<<dim3(12, 12), 256, 0, stream>>>(Wq, W2b, 0);
    split_wT<<<dim3(12, 12), 256, 0, stream>>>(Wk, W2b, 768);
    split_wT<<<dim3(12, 12), 256, 0, stream>>>(Wv, W2b, 1536);

    // 3) fused QKV GEMM (M=4096, N=2304, K=2304)
    mfma_gemm<1><<<dim3(18, 32), 256, 0, stream>>>(A2, W2b, bq, bk, bv, Qb, Kb, Vb);

    // 4) bias tensor (fp16)
    bias_mlp<<<dim3(1024, 4), 256, 0, stream>>>(pos, W1, b1, W2, b2, BiasH);

    // 5) attention
    attn_fused<<<dim3(16, 48), 256, 0, stream>>>(Qb, Kb, Vb, BiasH, AOb);

    // 6) split AO and Wo (reuse A2 / W2 buffers)
    split_hi_lo<<<3072, 256, 0, stream>>>(AOb, A2);
    split_wT<<<dim3(12, 12), 256, 0, stream>>>(Wo, W2b, 0);

    // 7) output projection (M=4096, N=768, K=2304)
    mfma_gemm<0><<<dim3(6, 32), 256, 0, stream>>>(A2, W2b, bo, nullptr, nullptr, out,
                                                  nullptr, nullptr);
}

// Round 5
// 483.226 us; speedup vs baseline: 1.7860x; 1.0125x over previous
//
#include <hip/hip_runtime.h>

// SpatialAwareAttention — round 5: full-MFMA attention (bf16x2 split operands),
// fused in-kernel spatial MLP (bias tensor eliminated), bf16x3 MFMA GEMMs.
// B=4, L=1024, D=768, H=12, hd=64, BIAS_HIDDEN=32.
//
// Pipeline:
//   1) split_hi_lo : x -> A2[4096][2304] bf16 ([Ah|Ah|Al])
//   2) split_wT x3 : Wq/Wk/Wv -> W2b[2304 n][2304 k] bf16 ([Wh;Wl;Wh])
//   3) mfma_gemm<1>: QKV GEMM; epilogue emits split planes:
//        Qh/Ql (pre-scaled by 0.125), Kh/Kl  [bh][l][64]
//        Vth/Vtl [bh][d][1024] (transposed for PV B-operand)
//   4) attn_mfma   : flash attention, QK^T & PV on MFMA via split-bf16
//                    (2x2 chunk reuse, 6 MFMA per 16x16), MLP recomputed
//                    in-register (VALU overlaps MFMA pipe), epilogue writes
//                    A2 tripled bf16 directly.
//   5) split_wT(Wo); mfma_gemm<0>: out = A2 @ Wo^T + bo.

typedef unsigned short ushort_t;
typedef unsigned int uint_t;
typedef __attribute__((ext_vector_type(8))) short bf16x8;
typedef __attribute__((ext_vector_type(4))) float f32x4;

__device__ __forceinline__ ushort_t f2b(float f) {  // fp32 -> bf16 (RNE)
    union { float f; uint_t u; } v;
    v.f = f;
    uint_t r = v.u + 0x7fffu + ((v.u >> 16) & 1u);
    return (ushort_t)(r >> 16);
}
__device__ __forceinline__ float b2f(ushort_t b) {
    union { uint_t u; float f; } v;
    v.u = ((uint_t)b) << 16;
    return v.f;
}

__device__ __forceinline__ void gload16(const void* g, void* l) {
    __builtin_amdgcn_global_load_lds(
        (const __attribute__((address_space(1))) unsigned int*)g,
        (__attribute__((address_space(3))) unsigned int*)l, 16, 0, 0);
}

// ---------------------------------------------------------------------------
// X[4096][768] fp32 -> X2[4096][2304] bf16 as [hi | hi | lo]
// ---------------------------------------------------------------------------
__global__ __launch_bounds__(256) void split_hi_lo(const float* __restrict__ X,
                                                   ushort_t* __restrict__ X2) {
    const int idx = blockIdx.x * 256 + threadIdx.x;
    const int m = idx / 192, k4 = (idx - m * 192) * 4;
    float4 v = *(const float4*)&X[(size_t)m * 768 + k4];
    ushort4 hi, lo;
    hi.x = f2b(v.x); lo.x = f2b(v.x - b2f(hi.x));
    hi.y = f2b(v.y); lo.y = f2b(v.y - b2f(hi.y));
    hi.z = f2b(v.z); lo.z = f2b(v.z - b2f(hi.z));
    hi.w = f2b(v.w); lo.w = f2b(v.w - b2f(hi.w));
    ushort_t* row = X2 + (size_t)m * 2304;
    *(ushort4*)&row[k4]        = hi;
    *(ushort4*)&row[768 + k4]  = hi;
    *(ushort4*)&row[1536 + k4] = lo;
}

// ---------------------------------------------------------------------------
// W[768 k][768 n] fp32 -> Wt[n_base+n][2304 k] bf16 k-blocks [hi ; lo ; hi]
// ---------------------------------------------------------------------------
__global__ __launch_bounds__(256) void split_wT(const float* __restrict__ W,
                                                ushort_t* __restrict__ Wt,
                                                int n_base) {
    __shared__ float Ws[64][65];
    const int t = threadIdx.x;
    const int rr0 = blockIdx.x * 64, nn0 = blockIdx.y * 64;
    const int c = t & 63, r4 = t >> 6;
#pragma unroll
    for (int e = 0; e < 16; ++e) {
        const int r = r4 + e * 4;
        Ws[r][c] = W[(size_t)(rr0 + r) * 768 + nn0 + c];
    }
    __syncthreads();
#pragma unroll
    for (int e = 0; e < 16; ++e) {
        const int nloc = r4 + e * 4;
        const float v = Ws[c][nloc];
        const ushort_t h = f2b(v);
        const ushort_t l = f2b(v - b2f(h));
        ushort_t* rowp = Wt + (size_t)(n_base + nn0 + nloc) * 2304 + rr0 + c;
        rowp[0]    = h;
        rowp[768]  = l;
        rowp[1536] = h;
    }
}

// ---------------------------------------------------------------------------
// GEMM: C[4096 x N] = A2 @ Bt^T, MFMA bf16, 128x128 tile, BK=64.
// QKV=1: N=2304; epilogue splits values to bf16 planes (Q scaled 0.125;
//        V transposed). QKV=0: N=768 fp32 epilogue (+bias).
// ---------------------------------------------------------------------------
template <int QKV>
__global__ __launch_bounds__(256) void mfma_gemm(
    const ushort_t* __restrict__ A2, const ushort_t* __restrict__ Bt,
    const float* __restrict__ bv0, const float* __restrict__ bv1,
    const float* __restrict__ bv2, ushort_t* __restrict__ Qh,
    ushort_t* __restrict__ Ql, ushort_t* __restrict__ Kh,
    ushort_t* __restrict__ Kl, ushort_t* __restrict__ Vth,
    ushort_t* __restrict__ Vtl, float* __restrict__ C0) {
    __shared__ ushort_t As[128 * 64];
    __shared__ ushort_t Bs[128 * 64];

    const int t = threadIdx.x;
    const int w = t >> 6, lane = t & 63;
    const int n0 = blockIdx.x * 128, m0 = blockIdx.y * 128;
    const int wr = (w >> 1) * 64, wc = (w & 1) * 64;

    f32x4 acc[4][4];
#pragma unroll
    for (int i = 0; i < 4; ++i)
#pragma unroll
        for (int j = 0; j < 4; ++j) acc[i][j] = (f32x4){0.f, 0.f, 0.f, 0.f};

    const int srow = t >> 3;
    const int sslot = t & 7;

    for (int k0 = 0; k0 < 2304; k0 += 64) {
        __syncthreads();
#pragma unroll
        for (int it = 0; it < 4; ++it) {
            const int row = srow + it * 32;
            const int kk = k0 + (((sslot ^ (row & 7)) << 3));
            char* dstA = (char*)As + it * 4096 + w * 1024;
            char* dstB = (char*)Bs + it * 4096 + w * 1024;
            gload16(A2 + (size_t)(m0 + row) * 2304 + kk, dstA);
            gload16(Bt + (size_t)(n0 + row) * 2304 + kk, dstB);
        }
        __syncthreads();

#pragma unroll
        for (int kk = 0; kk < 2; ++kk) {
            bf16x8 a[4], b[4];
#pragma unroll
            for (int i = 0; i < 4; ++i) {
                const int ra = wr + i * 16 + (lane & 15);
                const int sa = ((kk << 2) + (lane >> 4)) ^ (ra & 7);
                a[i] = *(const bf16x8*)((const char*)As + ra * 128 + sa * 16);
                const int rb = wc + i * 16 + (lane & 15);
                const int sb = ((kk << 2) + (lane >> 4)) ^ (rb & 7);
                b[i] = *(const bf16x8*)((const char*)Bs + rb * 128 + sb * 16);
            }
#pragma unroll
            for (int i = 0; i < 4; ++i)
#pragma unroll
                for (int j = 0; j < 4; ++j)
                    acc[i][j] = __builtin_amdgcn_mfma_f32_16x16x32_bf16(
                        a[i], b[j], acc[i][j], 0, 0, 0);
        }
    }

    const int cl = lane & 15, rg = (lane >> 4) * 4;
    if constexpr (QKV) {
        const int which = n0 / 768;  // block never straddles a 768 boundary
        const int nb = n0 - which * 768 + wc;
        const float* bb = which == 0 ? bv0 : (which == 1 ? bv1 : bv2);
#pragma unroll
        for (int i = 0; i < 4; ++i)
#pragma unroll
            for (int j = 0; j < 4; ++j) {
                const int cw = nb + j * 16 + cl;     // 0..767
                const int h = cw >> 6, d = cw & 63;
                const float badd = bb[cw];
#pragma unroll
                for (int r = 0; r < 4; ++r) {
                    const int gr = m0 + wr + i * 16 + rg + r;
                    const int b = gr >> 10, l = gr & 1023;
                    const int bh = b * 12 + h;
                    float val = acc[i][j][r] + badd;
                    if (which == 0) val *= 0.125f;   // fold 1/sqrt(hd) into Q
                    const ushort_t hi = f2b(val);
                    const ushort_t lo = f2b(val - b2f(hi));
                    if (which == 0) {
                        const size_t idx = ((size_t)((bh << 10) + l)) * 64 + d;
                        Qh[idx] = hi; Ql[idx] = lo;
                    } else if (which == 1) {
                        const size_t idx = ((size_t)((bh << 10) + l)) * 64 + d;
                        Kh[idx] = hi; Kl[idx] = lo;
                    } else {
                        const size_t idx = (((size_t)((bh << 6) + d)) << 10) + l;
                        Vth[idx] = hi; Vtl[idx] = lo;
                    }
                }
            }
    } else {
#pragma unroll
        for (int i = 0; i < 4; ++i)
#pragma unroll
            for (int j = 0; j < 4; ++j) {
                const int gc = n0 + wc + j * 16 + cl;
#pragma unroll
                for (int r = 0; r < 4; ++r) {
                    const int gr = m0 + wr + i * 16 + rg + r;
                    C0[(size_t)gr * 768 + gc] = acc[i][j][r] + bv0[gc];
                }
            }
    }
}

// ---------------------------------------------------------------------------
// MFMA flash attention + fused spatial MLP.
// Grid 768 (XCD-chunk swizzled): block = (bh, i-tile of 64 rows), 4 waves.
// Wave w: rows [16w,16w+16). Split-bf16 QK^T and PV (6 MFMA / 16x16 block,
// 2x2 chunk reuse). K/V staged to LDS via swizzled-source global_load_lds;
// P transposed through wave-private swizzled LDS.
// ---------------------------------------------------------------------------
__global__ __launch_bounds__(256) void attn_mfma(
    const ushort_t* __restrict__ Qh, const ushort_t* __restrict__ Ql,
    const ushort_t* __restrict__ Kh, const ushort_t* __restrict__ Kl,
    const ushort_t* __restrict__ Vth, const ushort_t* __restrict__ Vtl,
    const float* __restrict__ pos, const float* __restrict__ W1,
    const float* __restrict__ b1, const float* __restrict__ W2,
    const float* __restrict__ b2, ushort_t* __restrict__ A2) {
    __shared__ ushort_t Kls[2][64][64];   // [plane h/l][j][d]
    __shared__ ushort_t Vls[2][64][64];   // [plane h/l][d][j]
    __shared__ ushort_t P2s[4][2][16][64]; // [wave][plane][row][j] swizzled
    __shared__ float2 posj[64];
    __shared__ float4 wpack[32];          // {W1x, W1y, b1, W2[:,h]}

    const int t = threadIdx.x;
    const int wgid0 = blockIdx.x;
    const int wgid = (wgid0 & 7) * 96 + (wgid0 >> 3);  // XCD chunk swizzle
    const int bh = wgid >> 4, it = wgid & 15;
    const int b = bh / 12, h = bh - b * 12;
    const int i0 = it << 6;
    const int w = t >> 6, l = t & 63;
    const int l4 = l >> 4, lm = l & 15;

    if (t < 32) wpack[t] = make_float4(W1[t], W1[32 + t], b1[t], W2[t * 12 + h]);
    const float b2v = b2[h];

    // pos_i for this lane's 4 rows (C/D row = l4*4+r within wave stripe)
    float pix[4], piy[4];
#pragma unroll
    for (int r = 0; r < 4; ++r) {
        float2 p = *(const float2*)&pos[((b << 10) + i0 + 16 * w + l4 * 4 + r) * 2];
        pix[r] = p.x; piy[r] = p.y;
    }

    // Q A-fragments (row = lm, k = l4*8 [+32]) — direct global, held in regs
    const size_t qoff = ((size_t)((bh << 10) + i0 + 16 * w + lm)) * 64 + l4 * 8;
    const bf16x8 qh0 = *(const bf16x8*)(Qh + qoff);
    const bf16x8 qh1 = *(const bf16x8*)(Qh + qoff + 32);
    const bf16x8 ql0 = *(const bf16x8*)(Ql + qoff);
    const bf16x8 ql1 = *(const bf16x8*)(Ql + qoff + 32);

    float m_[4], l_[4];
    f32x4 o_[4];
#pragma unroll
    for (int r = 0; r < 4; ++r) { m_[r] = -1e30f; l_[r] = 0.f; }
#pragma unroll
    for (int db = 0; db < 4; ++db) o_[db] = (f32x4){0.f, 0.f, 0.f, 0.f};

    for (int jt = 0; jt < 16; ++jt) {
        const int j0 = jt << 6;
        __syncthreads();  // prior tile's LDS reads complete
        if (t < 64) posj[t] = *(const float2*)&pos[((b << 10) + j0 + t) * 2];
        {   // wave w stages one 8KB plane: 0=Kh 1=Kl 2=Vth 3=Vtl
            ushort_t* lb = (w == 0) ? &Kls[0][0][0]
                         : (w == 1) ? &Kls[1][0][0]
                         : (w == 2) ? &Vls[0][0][0] : &Vls[1][0][0];
            const ushort_t* gt = (w == 0) ? Kh : (w == 1) ? Kl
                               : (w == 2) ? Vth : Vtl;
#pragma unroll
            for (int ch = 0; ch < 8; ++ch) {
                const int row = ch * 8 + (l >> 3);
                const int off8 = (((l & 7) ^ (row & 7)) << 3);
                const ushort_t* src =
                    (w < 2) ? gt + ((size_t)((bh << 10) + j0 + row)) * 64 + off8
                            : gt + ((size_t)((bh << 6) + row)) * 1024 + j0 + off8;
                gload16(src, (char*)lb + ch * 1024);
            }
        }
        __syncthreads();

        // ---- S = Q.K^T via split-bf16 (QhKh + QhKl + QlKh) ----
        f32x4 s_[4];
#pragma unroll
        for (int cb = 0; cb < 4; ++cb) {
            const int row = 16 * cb + lm;
            const int sw = row & 7;
            const char* k0p = (const char*)&Kls[0][0][0] + row * 128;
            const char* k1p = (const char*)&Kls[1][0][0] + row * 128;
            const bf16x8 kh0 = *(const bf16x8*)(k0p + ((l4 + 0) ^ sw) * 16);
            const bf16x8 kh1 = *(const bf16x8*)(k0p + ((l4 + 4) ^ sw) * 16);
            const bf16x8 kl0 = *(const bf16x8*)(k1p + ((l4 + 0) ^ sw) * 16);
            const bf16x8 kl1 = *(const bf16x8*)(k1p + ((l4 + 4) ^ sw) * 16);
            f32x4 a = (f32x4){0.f, 0.f, 0.f, 0.f};
            a = __builtin_amdgcn_mfma_f32_16x16x32_bf16(qh0, kh0, a, 0, 0, 0);
            a = __builtin_amdgcn_mfma_f32_16x16x32_bf16(qh1, kh1, a, 0, 0, 0);
            a = __builtin_amdgcn_mfma_f32_16x16x32_bf16(qh0, kl0, a, 0, 0, 0);
            a = __builtin_amdgcn_mfma_f32_16x16x32_bf16(qh1, kl1, a, 0, 0, 0);
            a = __builtin_amdgcn_mfma_f32_16x16x32_bf16(ql0, kh0, a, 0, 0, 0);
            a = __builtin_amdgcn_mfma_f32_16x16x32_bf16(ql1, kh1, a, 0, 0, 0);
            s_[cb] = a;
        }

        // ---- fused spatial MLP (VALU; overlaps MFMA pipe) ----
        f32x4 dxv[4], dyv[4], bx[4];
#pragma unroll
        for (int cb = 0; cb < 4; ++cb) {
            const float2 pj = posj[16 * cb + lm];
#pragma unroll
            for (int r = 0; r < 4; ++r) {
                dxv[cb][r] = pix[r] - pj.x;
                dyv[cb][r] = piy[r] - pj.y;
                bx[cb][r] = b2v;
            }
        }
#pragma unroll 8
        for (int u = 0; u < 32; ++u) {
            const float4 wp = wpack[u];
#pragma unroll
            for (int cb = 0; cb < 4; ++cb)
#pragma unroll
                for (int r = 0; r < 4; ++r) {
                    float hv = fmaf(dxv[cb][r], wp.x, fmaf(dyv[cb][r], wp.y, wp.z));
                    bx[cb][r] = fmaf(fmaxf(hv, 0.f), wp.w, bx[cb][r]);
                }
        }
#pragma unroll
        for (int cb = 0; cb < 4; ++cb)
#pragma unroll
            for (int r = 0; r < 4; ++r) s_[cb][r] += bx[cb][r];

        // ---- online softmax (row across lm: xor 1,2,4,8) ----
        float corr[4];
#pragma unroll
        for (int r = 0; r < 4; ++r) {
            float mx = fmaxf(fmaxf(s_[0][r], s_[1][r]), fmaxf(s_[2][r], s_[3][r]));
            mx = fmaxf(mx, __shfl_xor(mx, 1));
            mx = fmaxf(mx, __shfl_xor(mx, 2));
            mx = fmaxf(mx, __shfl_xor(mx, 4));
            mx = fmaxf(mx, __shfl_xor(mx, 8));
            const float mn = fmaxf(m_[r], mx);
            corr[r] = __expf(m_[r] - mn);
            m_[r] = mn;
            float ps = 0.f;
#pragma unroll
            for (int cb = 0; cb < 4; ++cb) {
                s_[cb][r] = __expf(s_[cb][r] - mn);
                ps += s_[cb][r];
            }
            ps += __shfl_xor(ps, 1);
            ps += __shfl_xor(ps, 2);
            ps += __shfl_xor(ps, 4);
            ps += __shfl_xor(ps, 8);
            l_[r] = fmaf(l_[r], corr[r], ps);
            o_[0][r] *= corr[r]; o_[1][r] *= corr[r];
            o_[2][r] *= corr[r]; o_[3][r] *= corr[r];
        }

        // ---- split P -> wave-private swizzled LDS (transpose C->A layout) --
        char* pw = (char*)&P2s[w][0][0][0];
#pragma unroll
        for (int cb = 0; cb < 4; ++cb)
#pragma unroll
            for (int r = 0; r < 4; ++r) {
                const float p = s_[cb][r];
                const ushort_t ph = f2b(p);
                const ushort_t pl = f2b(p - b2f(ph));
                const int rl = l4 * 4 + r;
                const int bo = rl * 128 + ((((lm >> 3) + 2 * cb) ^ (rl & 7)) << 4)
                               + ((2 * lm) & 15);
                *(ushort_t*)(pw + bo) = ph;
                *(ushort_t*)(pw + 2048 + bo) = pl;
            }

        // ---- P A-frags (same-wave LDS; compiler inserts lgkmcnt) ----
        const int psw = lm & 7;
        const char* pb = (const char*)&P2s[w][0][0][0] + lm * 128;
        const bf16x8 pa0 = *(const bf16x8*)(pb + ((l4 + 0) ^ psw) * 16);
        const bf16x8 pa1 = *(const bf16x8*)(pb + ((l4 + 4) ^ psw) * 16);
        const bf16x8 pb0 = *(const bf16x8*)(pb + 2048 + ((l4 + 0) ^ psw) * 16);
        const bf16x8 pb1 = *(const bf16x8*)(pb + 2048 + ((l4 + 4) ^ psw) * 16);

        // ---- O += P.V via split-bf16 (PhVh + PhVl + PlVh) ----
#pragma unroll
        for (int db = 0; db < 4; ++db) {
            const int vrow = 16 * db + lm;
            const int vw = vrow & 7;
            const char* v0p = (const char*)&Vls[0][0][0] + vrow * 128;
            const char* v1p = (const char*)&Vls[1][0][0] + vrow * 128;
            const bf16x8 vh0 = *(const bf16x8*)(v0p + ((l4 + 0) ^ vw) * 16);
            const bf16x8 vh1 = *(const bf16x8*)(v0p + ((l4 + 4) ^ vw) * 16);
            const bf16x8 vl0 = *(const bf16x8*)(v1p + ((l4 + 0) ^ vw) * 16);
            const bf16x8 vl1 = *(const bf16x8*)(v1p + ((l4 + 4) ^ vw) * 16);
            f32x4 a = o_[db];
            a = __builtin_amdgcn_mfma_f32_16x16x32_bf16(pa0, vh0, a, 0, 0, 0);
            a = __builtin_amdgcn_mfma_f32_16x16x32_bf16(pa1, vh1, a, 0, 0, 0);
            a = __builtin_amdgcn_mfma_f32_16x16x32_bf16(pa0, vl0, a, 0, 0, 0);
            a = __builtin_amdgcn_mfma_f32_16x16x32_bf16(pa1, vl1, a, 0, 0, 0);
            a = __builtin_amdgcn_mfma_f32_16x16x32_bf16(pb0, vh0, a, 0, 0, 0);
            a = __builtin_amdgcn_mfma_f32_16x16x32_bf16(pb1, vh1, a, 0, 0, 0);
            o_[db] = a;
        }
    }

    // ---- epilogue: normalize, split to bf16, write A2 tripled ----
    const int mrow = (b << 10) + i0 + 16 * w + l4 * 4;
#pragma unroll
    for (int r = 0; r < 4; ++r) {
        const float inv = 1.f / l_[r];
        ushort_t* rowp = A2 + (size_t)(mrow + r) * 2304;
#pragma unroll
        for (int db = 0; db < 4; ++db) {
            const float val = o_[db][r] * inv;
            const ushort_t hi = f2b(val);
            const ushort_t lo = f2b(val - b2f(hi));
            const int c = (h << 6) + 16 * db + lm;
            rowp[c] = hi;
            rowp[768 + c] = hi;
            rowp[1536 + c] = lo;
        }
    }
}

extern "C" void kernel_launch(void* const* d_in, const int* in_sizes, int n_in,
                              void* d_out, int out_size, void* d_ws, size_t ws_size,
                              hipStream_t stream) {
    const float* x   = (const float*)d_in[0];
    const float* pos = (const float*)d_in[1];
    const float* Wq  = (const float*)d_in[2];
    const float* bq  = (const float*)d_in[3];
    const float* Wk  = (const float*)d_in[4];
    const float* bk  = (const float*)d_in[5];
    const float* Wv  = (const float*)d_in[6];
    const float* bv  = (const float*)d_in[7];
    const float* Wo  = (const float*)d_in[8];
    const float* bo  = (const float*)d_in[9];
    const float* W1  = (const float*)d_in[10];
    const float* b1  = (const float*)d_in[11];
    const float* W2  = (const float*)d_in[12];
    const float* b2  = (const float*)d_in[13];
    float* out = (float*)d_out;

    // ws (all bf16): 6 split planes (6 x 6.29MB) | A2 18.9MB | W2b 10.6MB
    ushort_t* Qhb = (ushort_t*)d_ws;          // [48][1024][64]
    ushort_t* Qlb = Qhb + 3145728;
    ushort_t* Khb = Qlb + 3145728;
    ushort_t* Klb = Khb + 3145728;
    ushort_t* Vth = Klb + 3145728;            // [48][64][1024]
    ushort_t* Vtl = Vth + 3145728;
    ushort_t* A2  = Vtl + 3145728;            // [4096][2304]
    ushort_t* W2b = A2 + 9437184;             // [2304][2304]

    split_hi_lo<<<3072, 256, 0, stream>>>(x, A2);
    split_wT<<<dim3(12, 12), 256, 0, stream>>>(Wq, W2b, 0);
    split_wT<<<dim3(12, 12), 256, 0, stream>>>(Wk, W2b, 768);
    split_wT<<<dim3(12, 12), 256, 0, stream>>>(Wv, W2b, 1536);

    mfma_gemm<1><<<dim3(18, 32), 256, 0, stream>>>(
        A2, W2b, bq, bk, bv, Qhb, Qlb, Khb, Klb, Vth, Vtl, nullptr);

    attn_mfma<<<768, 256, 0, stream>>>(Qhb, Qlb, Khb, Klb, Vth, Vtl, pos, W1, b1,
                                       W2, b2, A2);

    split_wT<<<dim3(12, 12), 256, 0, stream>>>(Wo, W2b, 0);
    mfma_gemm<0><<<dim3(6, 32), 256, 0, stream>>>(
        A2, W2b, bo, nullptr, nullptr, nullptr, nullptr, nullptr, nullptr, nullptr,
        nullptr, out);
}

// Round 6
// 374.284 us; speedup vs baseline: 2.3059x; 1.2911x over previous
//
#include <hip/hip_runtime.h>
#include <hip/hip_fp16.h>

// SpatialAwareAttention — round 6: MFMA attention + precomputed fp16 bias
// (fused MLP removed from the hot loop: it was 75% VALU / 200µs of redundant
// per-head recompute). bf16x3 MFMA GEMMs unchanged.
//
// Pipeline:
//   1) split_hi_lo : x -> A2[4096][2304] bf16 ([Ah|Ah|Al])
//   2) split_wT x3 : Wq/Wk/Wv -> W2b[2304][2304] bf16 ([Wh;Wl;Wh])
//   3) mfma_gemm<1>: QKV GEMM; epilogue emits split bf16 planes
//        Qh/Ql (pre-scaled 0.125), Kh/Kl [bh][l][64]; Vth/Vtl [bh][d][1024]
//   4) bias_mlp    : bias[b][h][i][j] fp16 (hidden once per pair, 12 heads)
//   5) attn_mfma   : flash attention, QK^T & PV on MFMA (split-bf16, 6 MFMA
//                    per 16x16), bias loaded fp16; epilogue writes A2 tripled
//   6) split_wT(Wo); mfma_gemm<0>: out = A2 @ Wo^T + bo

typedef unsigned short ushort_t;
typedef unsigned int uint_t;
typedef __attribute__((ext_vector_type(8))) short bf16x8;
typedef __attribute__((ext_vector_type(4))) float f32x4;

__device__ __forceinline__ ushort_t f2b(float f) {  // fp32 -> bf16 (RNE)
    union { float f; uint_t u; } v;
    v.f = f;
    uint_t r = v.u + 0x7fffu + ((v.u >> 16) & 1u);
    return (ushort_t)(r >> 16);
}
__device__ __forceinline__ float b2f(ushort_t b) {
    union { uint_t u; float f; } v;
    v.u = ((uint_t)b) << 16;
    return v.f;
}

__device__ __forceinline__ void gload16(const void* g, void* l) {
    __builtin_amdgcn_global_load_lds(
        (const __attribute__((address_space(1))) unsigned int*)g,
        (__attribute__((address_space(3))) unsigned int*)l, 16, 0, 0);
}

// ---------------------------------------------------------------------------
// X[4096][768] fp32 -> X2[4096][2304] bf16 as [hi | hi | lo]
// ---------------------------------------------------------------------------
__global__ __launch_bounds__(256) void split_hi_lo(const float* __restrict__ X,
                                                   ushort_t* __restrict__ X2) {
    const int idx = blockIdx.x * 256 + threadIdx.x;
    const int m = idx / 192, k4 = (idx - m * 192) * 4;
    float4 v = *(const float4*)&X[(size_t)m * 768 + k4];
    ushort4 hi, lo;
    hi.x = f2b(v.x); lo.x = f2b(v.x - b2f(hi.x));
    hi.y = f2b(v.y); lo.y = f2b(v.y - b2f(hi.y));
    hi.z = f2b(v.z); lo.z = f2b(v.z - b2f(hi.z));
    hi.w = f2b(v.w); lo.w = f2b(v.w - b2f(hi.w));
    ushort_t* row = X2 + (size_t)m * 2304;
    *(ushort4*)&row[k4]        = hi;
    *(ushort4*)&row[768 + k4]  = hi;
    *(ushort4*)&row[1536 + k4] = lo;
}

// ---------------------------------------------------------------------------
// W[768 k][768 n] fp32 -> Wt[n_base+n][2304 k] bf16 k-blocks [hi ; lo ; hi]
// ---------------------------------------------------------------------------
__global__ __launch_bounds__(256) void split_wT(const float* __restrict__ W,
                                                ushort_t* __restrict__ Wt,
                                                int n_base) {
    __shared__ float Ws[64][65];
    const int t = threadIdx.x;
    const int rr0 = blockIdx.x * 64, nn0 = blockIdx.y * 64;
    const int c = t & 63, r4 = t >> 6;
#pragma unroll
    for (int e = 0; e < 16; ++e) {
        const int r = r4 + e * 4;
        Ws[r][c] = W[(size_t)(rr0 + r) * 768 + nn0 + c];
    }
    __syncthreads();
#pragma unroll
    for (int e = 0; e < 16; ++e) {
        const int nloc = r4 + e * 4;
        const float v = Ws[c][nloc];
        const ushort_t h = f2b(v);
        const ushort_t l = f2b(v - b2f(h));
        ushort_t* rowp = Wt + (size_t)(n_base + nn0 + nloc) * 2304 + rr0 + c;
        rowp[0]    = h;
        rowp[768]  = l;
        rowp[1536] = h;
    }
}

// ---------------------------------------------------------------------------
// GEMM: C[4096 x N] = A2 @ Bt^T, MFMA bf16, 128x128 tile, BK=64.
// ---------------------------------------------------------------------------
template <int QKV>
__global__ __launch_bounds__(256) void mfma_gemm(
    const ushort_t* __restrict__ A2, const ushort_t* __restrict__ Bt,
    const float* __restrict__ bv0, const float* __restrict__ bv1,
    const float* __restrict__ bv2, ushort_t* __restrict__ Qh,
    ushort_t* __restrict__ Ql, ushort_t* __restrict__ Kh,
    ushort_t* __restrict__ Kl, ushort_t* __restrict__ Vth,
    ushort_t* __restrict__ Vtl, float* __restrict__ C0) {
    __shared__ ushort_t As[128 * 64];
    __shared__ ushort_t Bs[128 * 64];

    const int t = threadIdx.x;
    const int w = t >> 6, lane = t & 63;
    const int n0 = blockIdx.x * 128, m0 = blockIdx.y * 128;
    const int wr = (w >> 1) * 64, wc = (w & 1) * 64;

    f32x4 acc[4][4];
#pragma unroll
    for (int i = 0; i < 4; ++i)
#pragma unroll
        for (int j = 0; j < 4; ++j) acc[i][j] = (f32x4){0.f, 0.f, 0.f, 0.f};

    const int srow = t >> 3;
    const int sslot = t & 7;

    for (int k0 = 0; k0 < 2304; k0 += 64) {
        __syncthreads();
#pragma unroll
        for (int it = 0; it < 4; ++it) {
            const int row = srow + it * 32;
            const int kk = k0 + (((sslot ^ (row & 7)) << 3));
            char* dstA = (char*)As + it * 4096 + w * 1024;
            char* dstB = (char*)Bs + it * 4096 + w * 1024;
            gload16(A2 + (size_t)(m0 + row) * 2304 + kk, dstA);
            gload16(Bt + (size_t)(n0 + row) * 2304 + kk, dstB);
        }
        __syncthreads();

#pragma unroll
        for (int kk = 0; kk < 2; ++kk) {
            bf16x8 a[4], b[4];
#pragma unroll
            for (int i = 0; i < 4; ++i) {
                const int ra = wr + i * 16 + (lane & 15);
                const int sa = ((kk << 2) + (lane >> 4)) ^ (ra & 7);
                a[i] = *(const bf16x8*)((const char*)As + ra * 128 + sa * 16);
                const int rb = wc + i * 16 + (lane & 15);
                const int sb = ((kk << 2) + (lane >> 4)) ^ (rb & 7);
                b[i] = *(const bf16x8*)((const char*)Bs + rb * 128 + sb * 16);
            }
#pragma unroll
            for (int i = 0; i < 4; ++i)
#pragma unroll
                for (int j = 0; j < 4; ++j)
                    acc[i][j] = __builtin_amdgcn_mfma_f32_16x16x32_bf16(
                        a[i], b[j], acc[i][j], 0, 0, 0);
        }
    }

    const int cl = lane & 15, rg = (lane >> 4) * 4;
    if constexpr (QKV) {
        const int which = n0 / 768;
        const int nb = n0 - which * 768 + wc;
        const float* bb = which == 0 ? bv0 : (which == 1 ? bv1 : bv2);
#pragma unroll
        for (int i = 0; i < 4; ++i)
#pragma unroll
            for (int j = 0; j < 4; ++j) {
                const int cw = nb + j * 16 + cl;
                const int h = cw >> 6, d = cw & 63;
                const float badd = bb[cw];
#pragma unroll
                for (int r = 0; r < 4; ++r) {
                    const int gr = m0 + wr + i * 16 + rg + r;
                    const int b = gr >> 10, l = gr & 1023;
                    const int bh = b * 12 + h;
                    float val = acc[i][j][r] + badd;
                    if (which == 0) val *= 0.125f;
                    const ushort_t hi = f2b(val);
                    const ushort_t lo = f2b(val - b2f(hi));
                    if (which == 0) {
                        const size_t idx = ((size_t)((bh << 10) + l)) * 64 + d;
                        Qh[idx] = hi; Ql[idx] = lo;
                    } else if (which == 1) {
                        const size_t idx = ((size_t)((bh << 10) + l)) * 64 + d;
                        Kh[idx] = hi; Kl[idx] = lo;
                    } else {
                        const size_t idx = (((size_t)((bh << 6) + d)) << 10) + l;
                        Vth[idx] = hi; Vtl[idx] = lo;
                    }
                }
            }
    } else {
#pragma unroll
        for (int i = 0; i < 4; ++i)
#pragma unroll
            for (int j = 0; j < 4; ++j) {
                const int gc = n0 + wc + j * 16 + cl;
#pragma unroll
                for (int r = 0; r < 4; ++r) {
                    const int gr = m0 + wr + i * 16 + rg + r;
                    C0[(size_t)gr * 768 + gc] = acc[i][j][r] + bv0[gc];
                }
            }
    }
}

// ---------------------------------------------------------------------------
// bias[b][h][i][j] = relu(delta_ij @ W1 + b1) @ W2[:,h] + b2[h] -> fp16
// Grid (1024 i, 4 b). Thread: j in {2t, 2t+1, 2t+512, 2t+513} (half2 stores).
// Hidden computed ONCE per pair, shared across all 12 heads.
// ---------------------------------------------------------------------------
__global__ __launch_bounds__(256) void bias_mlp(const float* __restrict__ pos,
                                                const float* __restrict__ W1,
                                                const float* __restrict__ b1,
                                                const float* __restrict__ W2,
                                                const float* __restrict__ b2,
                                                __half* __restrict__ Bias) {
    __shared__ float w1x[32], w1y[32], b1s[32], b2s[12];
    __shared__ float w2T[12][32];

    const int t = threadIdx.x;
    const int i = blockIdx.x;
    const int b = blockIdx.y;

    if (t < 32) { w1x[t] = W1[t]; w1y[t] = W1[32 + t]; b1s[t] = b1[t]; }
    if (t >= 32 && t < 44) b2s[t - 32] = b2[t - 32];
    for (int v = t; v < 384; v += 256) {
        const int u = v / 12, hh = v - u * 12;
        w2T[hh][u] = W2[v];
    }
    __syncthreads();

    const float2 pi2 = *(const float2*)&pos[((b << 10) + i) << 1];
    // j pairs: (2t, 2t+1) and (2t+512, 2t+513)
    const float4 pj01 = *(const float4*)&pos[((b << 10) + 2 * t) << 1];
    const float4 pj23 = *(const float4*)&pos[((b << 10) + 2 * t + 512) << 1];
    float dx[4], dy[4];
    dx[0] = pi2.x - pj01.x; dy[0] = pi2.y - pj01.y;
    dx[1] = pi2.x - pj01.z; dy[1] = pi2.y - pj01.w;
    dx[2] = pi2.x - pj23.x; dy[2] = pi2.y - pj23.y;
    dx[3] = pi2.x - pj23.z; dy[3] = pi2.y - pj23.w;

    float acc[4][12];
#pragma unroll
    for (int e = 0; e < 4; ++e)
#pragma unroll
        for (int h = 0; h < 12; ++h) acc[e][h] = b2s[h];

#pragma unroll
    for (int u4 = 0; u4 < 8; ++u4) {
        const float4 ax = *(const float4*)&w1x[u4 << 2];
        const float4 ay = *(const float4*)&w1y[u4 << 2];
        const float4 ab = *(const float4*)&b1s[u4 << 2];
        float4 hv[4];
#pragma unroll
        for (int e = 0; e < 4; ++e) {
            hv[e].x = fmaxf(fmaf(dx[e], ax.x, fmaf(dy[e], ay.x, ab.x)), 0.f);
            hv[e].y = fmaxf(fmaf(dx[e], ax.y, fmaf(dy[e], ay.y, ab.y)), 0.f);
            hv[e].z = fmaxf(fmaf(dx[e], ax.z, fmaf(dy[e], ay.z, ab.z)), 0.f);
            hv[e].w = fmaxf(fmaf(dx[e], ax.w, fmaf(dy[e], ay.w, ab.w)), 0.f);
        }
#pragma unroll
        for (int h = 0; h < 12; ++h) {
            const float4 wv = *(const float4*)&w2T[h][u4 << 2];
#pragma unroll
            for (int e = 0; e < 4; ++e)
                acc[e][h] = fmaf(hv[e].x, wv.x,
                            fmaf(hv[e].y, wv.y,
                            fmaf(hv[e].z, wv.z,
                            fmaf(hv[e].w, wv.w, acc[e][h]))));
        }
    }

    const size_t base = (((size_t)(b * 12)) << 20) + (((size_t)i) << 10);
#pragma unroll
    for (int h = 0; h < 12; ++h) {
        const size_t off = base + (((size_t)h) << 20);
        *(__half2*)&Bias[off + 2 * t]       = __floats2half2_rn(acc[0][h], acc[1][h]);
        *(__half2*)&Bias[off + 2 * t + 512] = __floats2half2_rn(acc[2][h], acc[3][h]);
    }
}

// ---------------------------------------------------------------------------
// MFMA flash attention; bias loaded from precomputed fp16 tensor.
// Grid 768 (XCD-chunk swizzled). 4 waves; wave w: rows [16w,16w+16).
// Split-bf16 QK^T and PV (6 MFMA / 16x16 block). LDS 48KB -> 3 blocks/CU.
// ---------------------------------------------------------------------------
__global__ __launch_bounds__(256) void attn_mfma(
    const ushort_t* __restrict__ Qh, const ushort_t* __restrict__ Ql,
    const ushort_t* __restrict__ Kh, const ushort_t* __restrict__ Kl,
    const ushort_t* __restrict__ Vth, const ushort_t* __restrict__ Vtl,
    const __half* __restrict__ BiasT, ushort_t* __restrict__ A2) {
    __shared__ ushort_t Kls[2][64][64];    // [plane h/l][j][d]
    __shared__ ushort_t Vls[2][64][64];    // [plane h/l][d][j]
    __shared__ ushort_t P2s[4][2][16][64]; // [wave][plane][row][j] swizzled

    const int t = threadIdx.x;
    const int wgid0 = blockIdx.x;
    const int wgid = (wgid0 & 7) * 96 + (wgid0 >> 3);  // XCD chunk swizzle
    const int bh = wgid >> 4, it = wgid & 15;
    const int b = bh / 12, h = bh - b * 12;
    const int i0 = it << 6;
    const int w = t >> 6, l = t & 63;
    const int l4 = l >> 4, lm = l & 15;

    // bias row base for this lane: rows i0+16w+l4*4+r, col offset lm
    const __half* bp = BiasT + (((size_t)bh) << 20) +
                       (((size_t)(i0 + 16 * w + l4 * 4)) << 10) + lm;

    // Q A-fragments (row = lm, k = l4*8 [+32]) — held in registers
    const size_t qoff = ((size_t)((bh << 10) + i0 + 16 * w + lm)) * 64 + l4 * 8;
    const bf16x8 qh0 = *(const bf16x8*)(Qh + qoff);
    const bf16x8 qh1 = *(const bf16x8*)(Qh + qoff + 32);
    const bf16x8 ql0 = *(const bf16x8*)(Ql + qoff);
    const bf16x8 ql1 = *(const bf16x8*)(Ql + qoff + 32);

    float m_[4], l_[4];
    f32x4 o_[4];
#pragma unroll
    for (int r = 0; r < 4; ++r) { m_[r] = -1e30f; l_[r] = 0.f; }
#pragma unroll
    for (int db = 0; db < 4; ++db) o_[db] = (f32x4){0.f, 0.f, 0.f, 0.f};

    for (int jt = 0; jt < 16; ++jt) {
        const int j0 = jt << 6;

        // ---- bias loads (issued early; consumed after QK^T) ----
        float bias_r[4][4];
#pragma unroll
        for (int cb = 0; cb < 4; ++cb)
#pragma unroll
            for (int r = 0; r < 4; ++r)
                bias_r[cb][r] = __half2float(bp[(r << 10) + j0 + 16 * cb]);

        __syncthreads();  // prior tile's LDS reads complete
        {   // wave w stages one 8KB plane: 0=Kh 1=Kl 2=Vth 3=Vtl
            ushort_t* lb = (w == 0) ? &Kls[0][0][0]
                         : (w == 1) ? &Kls[1][0][0]
                         : (w == 2) ? &Vls[0][0][0] : &Vls[1][0][0];
            const ushort_t* gt = (w == 0) ? Kh : (w == 1) ? Kl
                               : (w == 2) ? Vth : Vtl;
#pragma unroll
            for (int ch = 0; ch < 8; ++ch) {
                const int row = ch * 8 + (l >> 3);
                const int off8 = (((l & 7) ^ (row & 7)) << 3);
                const ushort_t* src =
                    (w < 2) ? gt + ((size_t)((bh << 10) + j0 + row)) * 64 + off8
                            : gt + ((size_t)((bh << 6) + row)) * 1024 + j0 + off8;
                gload16(src, (char*)lb + ch * 1024);
            }
        }
        __syncthreads();

        // ---- S = Q.K^T via split-bf16 (QhKh + QhKl + QlKh) ----
        f32x4 s_[4];
#pragma unroll
        for (int cb = 0; cb < 4; ++cb) {
            const int row = 16 * cb + lm;
            const int sw = row & 7;
            const char* k0p = (const char*)&Kls[0][0][0] + row * 128;
            const char* k1p = (const char*)&Kls[1][0][0] + row * 128;
            const bf16x8 kh0 = *(const bf16x8*)(k0p + ((l4 + 0) ^ sw) * 16);
            const bf16x8 kh1 = *(const bf16x8*)(k0p + ((l4 + 4) ^ sw) * 16);
            const bf16x8 kl0 = *(const bf16x8*)(k1p + ((l4 + 0) ^ sw) * 16);
            const bf16x8 kl1 = *(const bf16x8*)(k1p + ((l4 + 4) ^ sw) * 16);
            f32x4 a = (f32x4){0.f, 0.f, 0.f, 0.f};
            a = __builtin_amdgcn_mfma_f32_16x16x32_bf16(qh0, kh0, a, 0, 0, 0);
            a = __builtin_amdgcn_mfma_f32_16x16x32_bf16(qh1, kh1, a, 0, 0, 0);
            a = __builtin_amdgcn_mfma_f32_16x16x32_bf16(qh0, kl0, a, 0, 0, 0);
            a = __builtin_amdgcn_mfma_f32_16x16x32_bf16(qh1, kl1, a, 0, 0, 0);
            a = __builtin_amdgcn_mfma_f32_16x16x32_bf16(ql0, kh0, a, 0, 0, 0);
            a = __builtin_amdgcn_mfma_f32_16x16x32_bf16(ql1, kh1, a, 0, 0, 0);
            s_[cb] = a;
        }

        // ---- add precomputed bias ----
#pragma unroll
        for (int cb = 0; cb < 4; ++cb)
#pragma unroll
            for (int r = 0; r < 4; ++r) s_[cb][r] += bias_r[cb][r];

        // ---- online softmax (row across lm: xor 1,2,4,8) ----
        float corr[4];
#pragma unroll
        for (int r = 0; r < 4; ++r) {
            float mx = fmaxf(fmaxf(s_[0][r], s_[1][r]), fmaxf(s_[2][r], s_[3][r]));
            mx = fmaxf(mx, __shfl_xor(mx, 1));
            mx = fmaxf(mx, __shfl_xor(mx, 2));
            mx = fmaxf(mx, __shfl_xor(mx, 4));
            mx = fmaxf(mx, __shfl_xor(mx, 8));
            const float mn = fmaxf(m_[r], mx);
            corr[r] = __expf(m_[r] - mn);
            m_[r] = mn;
            float ps = 0.f;
#pragma unroll
            for (int cb = 0; cb < 4; ++cb) {
                s_[cb][r] = __expf(s_[cb][r] - mn);
                ps += s_[cb][r];
            }
            ps += __shfl_xor(ps, 1);
            ps += __shfl_xor(ps, 2);
            ps += __shfl_xor(ps, 4);
            ps += __shfl_xor(ps, 8);
            l_[r] = fmaf(l_[r], corr[r], ps);
            o_[0][r] *= corr[r]; o_[1][r] *= corr[r];
            o_[2][r] *= corr[r]; o_[3][r] *= corr[r];
        }

        // ---- split P -> wave-private swizzled LDS (transpose C->A layout) --
        char* pw = (char*)&P2s[w][0][0][0];
#pragma unroll
        for (int cb = 0; cb < 4; ++cb)
#pragma unroll
            for (int r = 0; r < 4; ++r) {
                const float p = s_[cb][r];
                const ushort_t ph = f2b(p);
                const ushort_t pl = f2b(p - b2f(ph));
                const int rl = l4 * 4 + r;
                const int bo = rl * 128 + ((((lm >> 3) + 2 * cb) ^ (rl & 7)) << 4)
                               + ((2 * lm) & 15);
                *(ushort_t*)(pw + bo) = ph;
                *(ushort_t*)(pw + 2048 + bo) = pl;
            }

        // ---- P A-frags (same-wave LDS) ----
        const int psw = lm & 7;
        const char* pb = (const char*)&P2s[w][0][0][0] + lm * 128;
        const bf16x8 pa0 = *(const bf16x8*)(pb + ((l4 + 0) ^ psw) * 16);
        const bf16x8 pa1 = *(const bf16x8*)(pb + ((l4 + 4) ^ psw) * 16);
        const bf16x8 pb0 = *(const bf16x8*)(pb + 2048 + ((l4 + 0) ^ psw) * 16);
        const bf16x8 pb1 = *(const bf16x8*)(pb + 2048 + ((l4 + 4) ^ psw) * 16);

        // ---- O += P.V via split-bf16 (PhVh + PhVl + PlVh) ----
#pragma unroll
        for (int db = 0; db < 4; ++db) {
            const int vrow = 16 * db + lm;
            const int vw = vrow & 7;
            const char* v0p = (const char*)&Vls[0][0][0] + vrow * 128;
            const char* v1p = (const char*)&Vls[1][0][0] + vrow * 128;
            const bf16x8 vh0 = *(const bf16x8*)(v0p + ((l4 + 0) ^ vw) * 16);
            const bf16x8 vh1 = *(const bf16x8*)(v0p + ((l4 + 4) ^ vw) * 16);
            const bf16x8 vl0 = *(const bf16x8*)(v1p + ((l4 + 0) ^ vw) * 16);
            const bf16x8 vl1 = *(const bf16x8*)(v1p + ((l4 + 4) ^ vw) * 16);
            f32x4 a = o_[db];
            a = __builtin_amdgcn_mfma_f32_16x16x32_bf16(pa0, vh0, a, 0, 0, 0);
            a = __builtin_amdgcn_mfma_f32_16x16x32_bf16(pa1, vh1, a, 0, 0, 0);
            a = __builtin_amdgcn_mfma_f32_16x16x32_bf16(pa0, vl0, a, 0, 0, 0);
            a = __builtin_amdgcn_mfma_f32_16x16x32_bf16(pa1, vl1, a, 0, 0, 0);
            a = __builtin_amdgcn_mfma_f32_16x16x32_bf16(pb0, vh0, a, 0, 0, 0);
            a = __builtin_amdgcn_mfma_f32_16x16x32_bf16(pb1, vh1, a, 0, 0, 0);
            o_[db] = a;
        }
    }

    // ---- epilogue: normalize, split to bf16, write A2 tripled ----
    const int mrow = (b << 10) + i0 + 16 * w + l4 * 4;
#pragma unroll
    for (int r = 0; r < 4; ++r) {
        const float inv = 1.f / l_[r];
        ushort_t* rowp = A2 + (size_t)(mrow + r) * 2304;
#pragma unroll
        for (int db = 0; db < 4; ++db) {
            const float val = o_[db][r] * inv;
            const ushort_t hi = f2b(val);
            const ushort_t lo = f2b(val - b2f(hi));
            const int c = (h << 6) + 16 * db + lm;
            rowp[c] = hi;
            rowp[768 + c] = hi;
            rowp[1536 + c] = lo;
        }
    }
}

extern "C" void kernel_launch(void* const* d_in, const int* in_sizes, int n_in,
                              void* d_out, int out_size, void* d_ws, size_t ws_size,
                              hipStream_t stream) {
    const float* x   = (const float*)d_in[0];
    const float* pos = (const float*)d_in[1];
    const float* Wq  = (const float*)d_in[2];
    const float* bq  = (const float*)d_in[3];
    const float* Wk  = (const float*)d_in[4];
    const float* bk  = (const float*)d_in[5];
    const float* Wv  = (const float*)d_in[6];
    const float* bv  = (const float*)d_in[7];
    const float* Wo  = (const float*)d_in[8];
    const float* bo  = (const float*)d_in[9];
    const float* W1  = (const float*)d_in[10];
    const float* b1  = (const float*)d_in[11];
    const float* W2  = (const float*)d_in[12];
    const float* b2  = (const float*)d_in[13];
    float* out = (float*)d_out;

    // ws: 6 split planes | A2 | W2b | BiasH fp16 (100.7MB) — ~168 MB total
    ushort_t* Qhb = (ushort_t*)d_ws;          // [48][1024][64]
    ushort_t* Qlb = Qhb + 3145728;
    ushort_t* Khb = Qlb + 3145728;
    ushort_t* Klb = Khb + 3145728;
    ushort_t* Vth = Klb + 3145728;            // [48][64][1024]
    ushort_t* Vtl = Vth + 3145728;
    ushort_t* A2  = Vtl + 3145728;            // [4096][2304]
    ushort_t* W2b = A2 + 9437184;             // [2304][2304]
    __half* BiasH = (__half*)(W2b + 5308416); // [48][1024][1024]

    split_hi_lo<<<3072, 256, 0, stream>>>(x, A2);
    split_wT<<<dim3(12, 12), 256, 0, stream>>>(Wq, W2b, 0);
    split_wT<<<dim3(12, 12), 256, 0, stream>>>(Wk, W2b, 768);
    split_wT<<<dim3(12, 12), 256, 0, stream>>>(Wv, W2b, 1536);

    mfma_gemm<1><<<dim3(18, 32), 256, 0, stream>>>(
        A2, W2b, bq, bk, bv, Qhb, Qlb, Khb, Klb, Vth, Vtl, nullptr);

    bias_mlp<<<dim3(1024, 4), 256, 0, stream>>>(pos, W1, b1, W2, b2, BiasH);

    attn_mfma<<<768, 256, 0, stream>>>(Qhb, Qlb, Khb, Klb, Vth, Vtl, BiasH, A2);

    split_wT<<<dim3(12, 12), 256, 0, stream>>>(Wo, W2b, 0);
    mfma_gemm<0><<<dim3(6, 32), 256, 0, stream>>>(
        A2, W2b, bo, nullptr, nullptr, nullptr, nullptr, nullptr, nullptr, nullptr,
        nullptr, out);
}